// Round 2
// baseline (720.433 us; speedup 1.0000x reference)
//
#include <hip/hip_runtime.h>
#include <hip/hip_bf16.h>

#define DEV static __device__ __forceinline__

DEV float b2f(__hip_bfloat16 v) { return __bfloat162float(v); }

DEV float lrelu(float e) { return e > 0.f ? e : 0.2f * e; }

// Flag-dispatched load: f32 flag is wave-uniform (read once from ws flags).
DEV float loadF(const void* p, size_t i, int f32) {
    if (f32) return ((const float*)p)[i];
    return b2f(((const __hip_bfloat16*)p)[i]);
}

// ---------------- dtype detection ----------------
// Genuine bf16 normal data (|v| in ~[1e-4, 10]) never has exponent >= 0xC8
// nor denormals. fp32-stored data read as u16 halves shows ~22% such
// patterns in the low halves. >=1 insane sample => array is fp32.
__global__ __launch_bounds__(256) void k_detect(
    const void* a0, int n0, const void* a1, int n1, const void* a2, int n2,
    const void* a3, int n3, const void* a4, int n4, const void* a5, int n5,
    const void* a6, int n6, const void* a7, int n7, const void* a8, int n8,
    int* __restrict__ flags)
{
    const void* ps[9] = {a0,a1,a2,a3,a4,a5,a6,a7,a8};
    const int   ns[9] = {n0,n1,n2,n3,n4,n5,n6,n7,n8};
    __shared__ int cnt;
    for (int k = 0; k < 9; ++k) {
        if (threadIdx.x == 0) cnt = 0;
        __syncthreads();
        int samples = ns[k] < 256 ? ns[k] : 256;
        if ((int)threadIdx.x < samples) {
            unsigned short u = ((const unsigned short*)ps[k])[threadIdx.x];
            unsigned e = (u >> 7) & 0xFFu;
            bool insane = (e >= 0xC8u) || (e == 0u && (u & 0x7Fu) != 0u);
            if (insane) atomicAdd(&cnt, 1);
        }
        __syncthreads();
        if (threadIdx.x == 0) flags[k] = (cnt >= 1) ? 1 : 0;
        __syncthreads();
    }
}

// ---------------- layer-1 GEMM: h = x(N,128) @ W1(128,64), fused logits ----------------
__global__ __launch_bounds__(256) void k_gemm1(
    const void* __restrict__ x, const void* __restrict__ W,
    const void* __restrict__ a_s, const void* __restrict__ a_d,
    const int* __restrict__ flags,
    float* __restrict__ h, float* __restrict__ als, float* __restrict__ ald)
{
    __shared__ float sW[128 * 64];
    __shared__ float sX[4 * 128];
    const int tid = threadIdx.x;
    const int fx = flags[0], fw = flags[1], fas = flags[2], fad = flags[3];

    for (int i = tid; i < 128 * 64; i += 256) sW[i] = loadF(W, i, fw);
    const int row0 = blockIdx.x * 4;
    for (int i = tid; i < 4 * 128; i += 256) sX[i] = loadF(x, (size_t)row0 * 128 + i, fx);
    __syncthreads();

    const int r = tid >> 6, c = tid & 63;
    const float* xr = &sX[r * 128];
    float acc = 0.f;
#pragma unroll 8
    for (int k = 0; k < 128; ++k) acc = fmaf(xr[k], sW[k * 64 + c], acc);
    const int row = row0 + r;
    h[(size_t)row * 64 + c] = acc;

    float ps = acc * loadF(a_s, c, fas);
    float pd = acc * loadF(a_d, c, fad);
#pragma unroll
    for (int off = 32; off; off >>= 1) {
        ps += __shfl_xor(ps, off, 64);
        pd += __shfl_xor(pd, off, 64);
    }
    if (c == 0) { als[row] = ps; ald[row] = pd; }
}

// ---------------- layer-2 GEMM: h2 = relu(agg + b1) @ W2(64,64), fused logits ----------------
__global__ __launch_bounds__(256) void k_gemm2(
    const float* __restrict__ agg, const void* __restrict__ b1,
    const void* __restrict__ W, const void* __restrict__ a_s,
    const void* __restrict__ a_d, const int* __restrict__ flags,
    float* __restrict__ h, float* __restrict__ als, float* __restrict__ ald)
{
    __shared__ float sW[64 * 64];
    __shared__ float sX[4 * 64];
    const int tid = threadIdx.x;
    const int fb = flags[4], fw = flags[5], fas = flags[6], fad = flags[7];

    for (int i = tid; i < 64 * 64; i += 256) sW[i] = loadF(W, i, fw);
    const int row0 = blockIdx.x * 4;
    {
        float v = agg[(size_t)row0 * 64 + tid] + loadF(b1, tid & 63, fb);
        sX[tid] = v > 0.f ? v : 0.f;
    }
    __syncthreads();

    const int r = tid >> 6, c = tid & 63;
    const float* xr = &sX[r * 64];
    float acc = 0.f;
#pragma unroll 8
    for (int k = 0; k < 64; ++k) acc = fmaf(xr[k], sW[k * 64 + c], acc);
    const int row = row0 + r;
    h[(size_t)row * 64 + c] = acc;

    float ps = acc * loadF(a_s, c, fas);
    float pd = acc * loadF(a_d, c, fad);
#pragma unroll
    for (int off = 32; off; off >>= 1) {
        ps += __shfl_xor(ps, off, 64);
        pd += __shfl_xor(pd, off, 64);
    }
    if (c == 0) { als[row] = ps; ald[row] = pd; }
}

DEV void edge_sd(int i, int E, const int* __restrict__ src, const int* __restrict__ dst,
                 int& s, int& d) {
    if (i < E) { s = src[i]; d = dst[i]; }
    else       { s = d = i - E; }  // self-loops appended as arange(N)
}

// softmax without max-subtraction: logits are O(10), exp cannot overflow fp32,
// and exp(e)/sum(exp(e)) == exp(e-m)/sum(exp(e-m)) exactly in exact arithmetic.
__global__ __launch_bounds__(256) void k_edge_sum(
    const int* __restrict__ src, const int* __restrict__ dst,
    const float* __restrict__ als, const float* __restrict__ ald,
    float* __restrict__ denom, int E, int EA)
{
    int i = blockIdx.x * 256 + threadIdx.x;
    if (i >= EA) return;
    int s, d; edge_sd(i, E, src, dst, s, d);
    float e = lrelu(als[s] + ald[d]);
    atomicAdd(&denom[d], __expf(e));
}

// one wave per edge: lane f scatters h[s][f] * alpha into agg[d][f]
__global__ __launch_bounds__(256) void k_edge_agg(
    const int* __restrict__ src, const int* __restrict__ dst,
    const float* __restrict__ als, const float* __restrict__ ald,
    const float* __restrict__ denom, const float* __restrict__ h,
    float* __restrict__ agg, int E, int EA)
{
    const int tid = threadIdx.x;
    const int i = blockIdx.x * 4 + (tid >> 6);
    if (i >= EA) return;
    int s, d; edge_sd(i, E, src, dst, s, d);
    const int f = tid & 63;
    float e = lrelu(als[s] + ald[d]);          // uniform across the wave (broadcast loads)
    float coeff = __expf(e) / denom[d];
    atomicAdd(&agg[(size_t)d * 64 + f], h[(size_t)s * 64 + f] * coeff);
}

__global__ __launch_bounds__(256) void k_final(
    const float* __restrict__ agg, const void* __restrict__ b2,
    const int* __restrict__ flags, void* __restrict__ out, int total)
{
    int i = blockIdx.x * 256 + threadIdx.x;
    if (i >= total) return;
    float v = agg[i] + loadF(b2, i & 63, flags[8]);
    if (flags[0]) ((float*)out)[i] = v;
    else          ((__hip_bfloat16*)out)[i] = __float2bfloat16(v);
}

extern "C" void kernel_launch(void* const* d_in, const int* in_sizes, int n_in,
                              void* d_out, int out_size, void* d_ws, size_t ws_size,
                              hipStream_t stream)
{
    const void* x   = d_in[0];
    const int*  ei  = (const int*)d_in[1];
    const void* W1  = d_in[2];
    const void* as1 = d_in[3];
    const void* ad1 = d_in[4];
    const void* b1  = d_in[5];
    const void* W2  = d_in[6];
    const void* as2 = d_in[7];
    const void* ad2 = d_in[8];
    const void* b2  = d_in[9];

    const int N  = in_sizes[0] / 128;   // 50000
    const int E  = in_sizes[1] / 2;     // 800000
    const int EA = E + N;               // + self loops
    const int* src = ei;
    const int* dst = ei + E;

    int*   flags  = (int*)d_ws;                 // 16 ints (pad to 64 floats)
    float* ws     = (float*)d_ws;
    float* h      = ws + 64;                    // N*64
    float* agg    = h + (size_t)N * 64;         // N*64
    float* als    = agg + (size_t)N * 64;       // N
    float* ald    = als + N;                    // N
    float* denom  = ald + N;                    // N

    const int eb = (EA + 255) / 256;
    const int ab = (EA + 3) / 4;

    k_detect<<<1, 256, 0, stream>>>(
        x, in_sizes[0], W1, in_sizes[2], as1, in_sizes[3], ad1, in_sizes[4],
        b1, in_sizes[5], W2, in_sizes[6], as2, in_sizes[7], ad2, in_sizes[8],
        b2, in_sizes[9], flags);

    // ---- layer 1 ----
    hipMemsetAsync(denom, 0, (size_t)N * 4, stream);
    hipMemsetAsync(agg, 0, (size_t)N * 64 * 4, stream);
    k_gemm1<<<N / 4, 256, 0, stream>>>(x, W1, as1, ad1, flags, h, als, ald);
    k_edge_sum<<<eb, 256, 0, stream>>>(src, dst, als, ald, denom, E, EA);
    k_edge_agg<<<ab, 256, 0, stream>>>(src, dst, als, ald, denom, h, agg, E, EA);

    // ---- layer 2 (h buffer reused for h2) ----
    k_gemm2<<<N / 4, 256, 0, stream>>>(agg, b1, W2, as2, ad2, flags, h, als, ald);
    hipMemsetAsync(denom, 0, (size_t)N * 4, stream);
    hipMemsetAsync(agg, 0, (size_t)N * 64 * 4, stream);
    k_edge_sum<<<eb, 256, 0, stream>>>(src, dst, als, ald, denom, E, EA);
    k_edge_agg<<<ab, 256, 0, stream>>>(src, dst, als, ald, denom, h, agg, E, EA);

    k_final<<<(N * 64 + 255) / 256, 256, 0, stream>>>(agg, b2, flags, d_out, N * 64);
}

// Round 3
// 440.330 us; speedup vs baseline: 1.6361x; 1.6361x over previous
//
#include <hip/hip_runtime.h>
#include <hip/hip_bf16.h>

#define DEV static __device__ __forceinline__

DEV float b2f(__hip_bfloat16 v) { return __bfloat162float(v); }
DEV float lrelu(float e) { return e > 0.f ? e : 0.2f * e; }

// Flag-dispatched load (flag is wave-uniform).
DEV float loadF(const void* p, size_t i, int f32) {
    if (f32) return ((const float*)p)[i];
    return b2f(((const __hip_bfloat16*)p)[i]);
}

// ---------------- dtype detection (validated round 2) ----------------
__global__ __launch_bounds__(256) void k_detect(
    const void* a0, int n0, const void* a1, int n1, const void* a2, int n2,
    const void* a3, int n3, const void* a4, int n4, const void* a5, int n5,
    const void* a6, int n6, const void* a7, int n7, const void* a8, int n8,
    int* __restrict__ flags)
{
    const void* ps[9] = {a0,a1,a2,a3,a4,a5,a6,a7,a8};
    const int   ns[9] = {n0,n1,n2,n3,n4,n5,n6,n7,n8};
    __shared__ int cnt;
    for (int k = 0; k < 9; ++k) {
        if (threadIdx.x == 0) cnt = 0;
        __syncthreads();
        int samples = ns[k] < 256 ? ns[k] : 256;
        if ((int)threadIdx.x < samples) {
            unsigned short u = ((const unsigned short*)ps[k])[threadIdx.x];
            unsigned e = (u >> 7) & 0xFFu;
            bool insane = (e >= 0xC8u) || (e == 0u && (u & 0x7Fu) != 0u);
            if (insane) atomicAdd(&cnt, 1);
        }
        __syncthreads();
        if (threadIdx.x == 0) flags[k] = (cnt >= 1) ? 1 : 0;
        __syncthreads();
    }
}

DEV void edge_sd(int i, int E, const int* __restrict__ src, const int* __restrict__ dst,
                 int& s, int& d) {
    if (i < E) { s = src[i]; d = dst[i]; }
    else       { s = d = i - E; }  // self-loops appended as arange(N)
}

// ---------------- CSR build (once; graph shared by both layers) ----------------
__global__ __launch_bounds__(256) void k_degree(
    const int* __restrict__ src, const int* __restrict__ dst,
    int* __restrict__ deg, int E, int EA)
{
    int i = blockIdx.x * 256 + threadIdx.x;
    if (i >= EA) return;
    int s, d; edge_sd(i, E, src, dst, s, d);
    atomicAdd(&deg[d], 1);
}

__global__ __launch_bounds__(1024) void k_scan(
    const int* __restrict__ deg, int* __restrict__ row_ptr, int N)
{
    __shared__ int part[1024];
    const int tid = threadIdx.x;
    const int chunk = (N + 1023) / 1024;
    const int lo = tid * chunk;
    const int hi = (lo + chunk < N) ? lo + chunk : N;
    int s = 0;
    for (int i = lo; i < hi; ++i) s += deg[i];
    part[tid] = s;
    __syncthreads();
    for (int off = 1; off < 1024; off <<= 1) {
        int v = (tid >= off) ? part[tid - off] : 0;
        __syncthreads();
        part[tid] += v;
        __syncthreads();
    }
    int base = (tid == 0) ? 0 : part[tid - 1];
    for (int i = lo; i < hi; ++i) { row_ptr[i] = base; base += deg[i]; }
    if (tid == 1023) row_ptr[N] = part[1023];
}

__global__ __launch_bounds__(256) void k_fill(
    const int* __restrict__ src, const int* __restrict__ dst,
    const int* __restrict__ row_ptr, int* __restrict__ cursor,
    int* __restrict__ col, int E, int EA)
{
    int i = blockIdx.x * 256 + threadIdx.x;
    if (i >= EA) return;
    int s, d; edge_sd(i, E, src, dst, s, d);
    int pos = atomicAdd(&cursor[d], 1);
    col[row_ptr[d] + pos] = s;
}

// ---------------- layer-1 GEMM: h = x(N,128)@W1(128,64), 16 rows/block, fused logits ----------------
__global__ __launch_bounds__(256) void k_gemm1(
    const void* __restrict__ x, const void* __restrict__ W,
    const void* __restrict__ a_s, const void* __restrict__ a_d,
    const int* __restrict__ flags,
    __hip_bfloat16* __restrict__ h, float* __restrict__ als, float* __restrict__ ald)
{
    __shared__ float sW[128 * 64];
    __shared__ float sX[16 * 128];
    const int tid = threadIdx.x;
    const int fx = flags[0], fw = flags[1], fas = flags[2], fad = flags[3];
    for (int i = tid; i < 128 * 64; i += 256) sW[i] = loadF(W, i, fw);
    const int row0 = blockIdx.x * 16;
    for (int i = tid; i < 16 * 128; i += 256) sX[i] = loadF(x, (size_t)row0 * 128 + i, fx);
    __syncthreads();

    const int w = tid >> 6, f = tid & 63;
    float acc[4] = {0.f, 0.f, 0.f, 0.f};
    const float* xb = &sX[(w * 4) * 128];
#pragma unroll 4
    for (int k = 0; k < 128; ++k) {
        float wv = sW[k * 64 + f];
        acc[0] = fmaf(xb[k],       wv, acc[0]);
        acc[1] = fmaf(xb[128 + k], wv, acc[1]);
        acc[2] = fmaf(xb[256 + k], wv, acc[2]);
        acc[3] = fmaf(xb[384 + k], wv, acc[3]);
    }
    const float asf = loadF(a_s, f, fas), adf = loadF(a_d, f, fad);
#pragma unroll
    for (int j = 0; j < 4; ++j) {
        const int row = row0 + w * 4 + j;
        h[(size_t)row * 64 + f] = __float2bfloat16(acc[j]);
        float ps = acc[j] * asf, pd = acc[j] * adf;
#pragma unroll
        for (int off = 32; off; off >>= 1) {
            ps += __shfl_xor(ps, off, 64);
            pd += __shfl_xor(pd, off, 64);
        }
        if (f == 0) { als[row] = ps; ald[row] = pd; }
    }
}

// ---------------- layer-2 GEMM: h2 = relu(agg+b1)@W2(64,64), in-place on agg ----------------
__global__ __launch_bounds__(256) void k_gemm2(
    __hip_bfloat16* __restrict__ agg, const void* __restrict__ b1,
    const void* __restrict__ W, const void* __restrict__ a_s,
    const void* __restrict__ a_d, const int* __restrict__ flags,
    float* __restrict__ als, float* __restrict__ ald)
{
    __shared__ float sW[64 * 64];
    __shared__ float sX[16 * 64];
    const int tid = threadIdx.x;
    const int fb = flags[4], fw = flags[5], fas = flags[6], fad = flags[7];
    for (int i = tid; i < 64 * 64; i += 256) sW[i] = loadF(W, i, fw);
    const int row0 = blockIdx.x * 16;
    for (int i = tid; i < 16 * 64; i += 256) {
        float v = b2f(agg[(size_t)row0 * 64 + i]) + loadF(b1, i & 63, fb);
        sX[i] = v > 0.f ? v : 0.f;
    }
    __syncthreads();

    const int w = tid >> 6, f = tid & 63;
    float acc[4] = {0.f, 0.f, 0.f, 0.f};
    const float* xb = &sX[(w * 4) * 64];
#pragma unroll 4
    for (int k = 0; k < 64; ++k) {
        float wv = sW[k * 64 + f];
        acc[0] = fmaf(xb[k],       wv, acc[0]);
        acc[1] = fmaf(xb[64 + k],  wv, acc[1]);
        acc[2] = fmaf(xb[128 + k], wv, acc[2]);
        acc[3] = fmaf(xb[192 + k], wv, acc[3]);
    }
    const float asf = loadF(a_s, f, fas), adf = loadF(a_d, f, fad);
#pragma unroll
    for (int j = 0; j < 4; ++j) {
        const int row = row0 + w * 4 + j;
        agg[(size_t)row * 64 + f] = __float2bfloat16(acc[j]);  // in-place: block owns these rows
        float ps = acc[j] * asf, pd = acc[j] * adf;
#pragma unroll
        for (int off = 32; off; off >>= 1) {
            ps += __shfl_xor(ps, off, 64);
            pd += __shfl_xor(pd, off, 64);
        }
        if (f == 0) { als[row] = ps; ald[row] = pd; }
    }
}

// ---------------- CSR gather: one wave per dst node, atomic-free ----------------
// softmax w/o max-subtraction: logits are O(10) (validated round 2)
__global__ __launch_bounds__(256) void k_gather(
    const int* __restrict__ row_ptr, const int* __restrict__ col,
    const float* __restrict__ als, const float* __restrict__ ald,
    const __hip_bfloat16* __restrict__ h,
    __hip_bfloat16* __restrict__ agg_out,   // layer-1 mode (final_out == null)
    void* __restrict__ final_out,           // layer-2 mode: write d_out with bias
    const void* __restrict__ bias, const int* __restrict__ flags, int N)
{
    const int tid = threadIdx.x;
    const int d = blockIdx.x * 4 + (tid >> 6);
    if (d >= N) return;
    const int f = tid & 63;
    const float aldd = ald[d];
    int j = row_ptr[d];
    const int end = row_ptr[d + 1];
    float acc = 0.f, den = 0.f;
    // 2-wide unroll: two independent gather chains in flight
    for (; j + 1 < end; j += 2) {
        int s0 = col[j], s1 = col[j + 1];
        float h0 = b2f(h[(size_t)s0 * 64 + f]);
        float h1 = b2f(h[(size_t)s1 * 64 + f]);
        float w0 = __expf(lrelu(als[s0] + aldd));
        float w1 = __expf(lrelu(als[s1] + aldd));
        acc = fmaf(w0, h0, acc);
        acc = fmaf(w1, h1, acc);
        den += w0 + w1;
    }
    if (j < end) {
        int s = col[j];
        float w = __expf(lrelu(als[s] + aldd));
        acc = fmaf(w, b2f(h[(size_t)s * 64 + f]), acc);
        den += w;
    }
    float v = acc / den;
    if (final_out) {
        v += loadF(bias, f, flags[8]);
        if (flags[0]) ((float*)final_out)[(size_t)d * 64 + f] = v;
        else ((__hip_bfloat16*)final_out)[(size_t)d * 64 + f] = __float2bfloat16(v);
    } else {
        agg_out[(size_t)d * 64 + f] = __float2bfloat16(v);
    }
}

extern "C" void kernel_launch(void* const* d_in, const int* in_sizes, int n_in,
                              void* d_out, int out_size, void* d_ws, size_t ws_size,
                              hipStream_t stream)
{
    const void* x   = d_in[0];
    const int*  ei  = (const int*)d_in[1];
    const void* W1  = d_in[2];
    const void* as1 = d_in[3];
    const void* ad1 = d_in[4];
    const void* b1  = d_in[5];
    const void* W2  = d_in[6];
    const void* as2 = d_in[7];
    const void* ad2 = d_in[8];
    const void* b2  = d_in[9];

    const int N  = in_sizes[0] / 128;   // 50000
    const int E  = in_sizes[1] / 2;     // 800000
    const int EA = E + N;
    const int* src = ei;
    const int* dst = ei + E;

    // workspace layout (~17.3 MB)
    int*   flags   = (int*)d_ws;                          // 64 ints pad
    float* als     = (float*)d_ws + 64;                   // N
    float* ald     = als + N;                             // N
    int*   row_ptr = (int*)(ald + N);                     // N+1
    int*   deg_cur = row_ptr + (N + 1);                   // N
    int*   col     = deg_cur + N;                         // EA
    __hip_bfloat16* hbuf   = (__hip_bfloat16*)(col + EA); // N*64
    __hip_bfloat16* aggbuf = hbuf + (size_t)N * 64;       // N*64

    const int eb = (EA + 255) / 256;
    const int nb = (N + 3) / 4;        // gather blocks (4 waves each)
    const int gb = N / 16;             // gemm blocks (N divisible by 16 for N=50000... use ceil)
    const int gb1 = (N + 15) / 16;

    k_detect<<<1, 256, 0, stream>>>(
        x, in_sizes[0], W1, in_sizes[2], as1, in_sizes[3], ad1, in_sizes[4],
        b1, in_sizes[5], W2, in_sizes[6], as2, in_sizes[7], ad2, in_sizes[8],
        b2, in_sizes[9], flags);

    // ---- CSR build (once) ----
    hipMemsetAsync(deg_cur, 0, (size_t)N * 4, stream);
    k_degree<<<eb, 256, 0, stream>>>(src, dst, deg_cur, E, EA);
    k_scan<<<1, 1024, 0, stream>>>(deg_cur, row_ptr, N);
    hipMemsetAsync(deg_cur, 0, (size_t)N * 4, stream);
    k_fill<<<eb, 256, 0, stream>>>(src, dst, row_ptr, deg_cur, col, E, EA);

    // ---- layer 1 ----
    k_gemm1<<<gb1, 256, 0, stream>>>(x, W1, as1, ad1, flags, hbuf, als, ald);
    k_gather<<<nb, 256, 0, stream>>>(row_ptr, col, als, ald, hbuf, aggbuf,
                                     nullptr, nullptr, flags, N);
    // ---- layer 2 ----
    k_gemm2<<<gb1, 256, 0, stream>>>(aggbuf, b1, W2, as2, ad2, flags, als, ald);
    k_gather<<<nb, 256, 0, stream>>>(row_ptr, col, als, ald, aggbuf, nullptr,
                                     d_out, b2, flags, N);
    (void)gb; (void)out_size; (void)ws_size; (void)n_in;
}

// Round 4
// 330.210 us; speedup vs baseline: 2.1817x; 1.3335x over previous
//
#include <hip/hip_runtime.h>
#include <hip/hip_bf16.h>

#define DEV static __device__ __forceinline__

DEV float b2f(__hip_bfloat16 v) { return __bfloat162float(v); }
DEV float lrelu(float e) { return e > 0.f ? e : 0.2f * e; }

DEV unsigned short f2bu(float f) {
    __hip_bfloat16 b = __float2bfloat16(f);
    return *reinterpret_cast<unsigned short*>(&b);
}

// Flag-dispatched load (flag is wave-uniform).
DEV float loadF(const void* p, size_t i, int f32) {
    if (f32) return ((const float*)p)[i];
    return b2f(((const __hip_bfloat16*)p)[i]);
}

// ---------------- dtype detection (validated round 2/3) ----------------
__global__ __launch_bounds__(256) void k_detect(
    const void* a0, int n0, const void* a1, int n1, const void* a2, int n2,
    const void* a3, int n3, const void* a4, int n4, const void* a5, int n5,
    const void* a6, int n6, const void* a7, int n7, const void* a8, int n8,
    int* __restrict__ flags)
{
    const void* ps[9] = {a0,a1,a2,a3,a4,a5,a6,a7,a8};
    const int   ns[9] = {n0,n1,n2,n3,n4,n5,n6,n7,n8};
    __shared__ int cnt;
    for (int k = 0; k < 9; ++k) {
        if (threadIdx.x == 0) cnt = 0;
        __syncthreads();
        int samples = ns[k] < 256 ? ns[k] : 256;
        if ((int)threadIdx.x < samples) {
            unsigned short u = ((const unsigned short*)ps[k])[threadIdx.x];
            unsigned e = (u >> 7) & 0xFFu;
            bool insane = (e >= 0xC8u) || (e == 0u && (u & 0x7Fu) != 0u);
            if (insane) atomicAdd(&cnt, 1);
        }
        __syncthreads();
        if (threadIdx.x == 0) flags[k] = (cnt >= 1) ? 1 : 0;
        __syncthreads();
    }
}

DEV void edge_sd(int i, int E, const int* __restrict__ src, const int* __restrict__ dst,
                 int& s, int& d) {
    if (i < E) { s = src[i]; d = dst[i]; }
    else       { s = d = i - E; }  // self-loops appended as arange(N)
}

// ---------------- CSR build ----------------
__global__ __launch_bounds__(256) void k_degree(
    const int* __restrict__ src, const int* __restrict__ dst,
    int* __restrict__ deg, int E, int EA)
{
    int i = blockIdx.x * 256 + threadIdx.x;
    if (i >= EA) return;
    int s, d; edge_sd(i, E, src, dst, s, d);
    atomicAdd(&deg[d], 1);
}

// 3-phase parallel exclusive scan over N+1 positions
__global__ __launch_bounds__(256) void k_scan_blk(
    const int* __restrict__ deg, int* __restrict__ row_ptr,
    int* __restrict__ bsum, int N)
{
    __shared__ int sm[256];
    const int tid = threadIdx.x;
    const int gid = blockIdx.x * 256 + tid;
    int v = (gid < N) ? deg[gid] : 0;
    sm[tid] = v;
    __syncthreads();
#pragma unroll
    for (int off = 1; off < 256; off <<= 1) {
        int t = (tid >= off) ? sm[tid - off] : 0;
        __syncthreads();
        sm[tid] += t;
        __syncthreads();
    }
    if (gid <= N) row_ptr[gid] = sm[tid] - v;       // exclusive prefix within block
    if (tid == 255) bsum[blockIdx.x] = sm[255];     // block total
}

__global__ __launch_bounds__(256) void k_scan_top(int* __restrict__ bsum, int SB)
{
    __shared__ int sm[256];
    const int tid = threadIdx.x;
    const int chunk = (SB + 255) / 256;
    const int lo = tid * chunk;
    const int hi = (lo + chunk < SB) ? lo + chunk : SB;
    int s = 0;
    for (int i = lo; i < hi; ++i) s += bsum[i];
    sm[tid] = s;
    __syncthreads();
#pragma unroll
    for (int off = 1; off < 256; off <<= 1) {
        int t = (tid >= off) ? sm[tid - off] : 0;
        __syncthreads();
        sm[tid] += t;
        __syncthreads();
    }
    int base = tid ? sm[tid - 1] : 0;
    for (int i = lo; i < hi; ++i) { int t = bsum[i]; bsum[i] = base; base += t; }
}

__global__ __launch_bounds__(256) void k_scan_add(
    int* __restrict__ row_ptr, const int* __restrict__ bsum, int N)
{
    int gid = blockIdx.x * 256 + threadIdx.x;
    if (gid <= N) row_ptr[gid] += bsum[blockIdx.x];
}

__global__ __launch_bounds__(256) void k_fill(
    const int* __restrict__ src, const int* __restrict__ dst,
    const int* __restrict__ row_ptr, int* __restrict__ cursor,
    int* __restrict__ col, int E, int EA)
{
    int i = blockIdx.x * 256 + threadIdx.x;
    if (i >= EA) return;
    int s, d; edge_sd(i, E, src, dst, s, d);
    int pos = atomicAdd(&cursor[d], 1);
    col[row_ptr[d] + pos] = s;
}

// ---------------- layer-1 GEMM: h = x(N,128)@W1(128,64), fused logits ----------------
__global__ __launch_bounds__(256) void k_gemm1(
    const void* __restrict__ x, const void* __restrict__ W,
    const void* __restrict__ a_s, const void* __restrict__ a_d,
    const int* __restrict__ flags,
    __hip_bfloat16* __restrict__ h, float* __restrict__ als, float* __restrict__ ald)
{
    __shared__ float sW[128 * 64];
    __shared__ float sX[16 * 128];
    const int tid = threadIdx.x;
    const int fx = flags[0], fw = flags[1], fas = flags[2], fad = flags[3];
    for (int i = tid; i < 128 * 64; i += 256) sW[i] = loadF(W, i, fw);
    const int row0 = blockIdx.x * 16;
    for (int i = tid; i < 16 * 128; i += 256) sX[i] = loadF(x, (size_t)row0 * 128 + i, fx);
    __syncthreads();

    const int w = tid >> 6, f = tid & 63;
    float acc[4] = {0.f, 0.f, 0.f, 0.f};
    const float* xb = &sX[(w * 4) * 128];
#pragma unroll 4
    for (int k = 0; k < 128; ++k) {
        float wv = sW[k * 64 + f];
        acc[0] = fmaf(xb[k],       wv, acc[0]);
        acc[1] = fmaf(xb[128 + k], wv, acc[1]);
        acc[2] = fmaf(xb[256 + k], wv, acc[2]);
        acc[3] = fmaf(xb[384 + k], wv, acc[3]);
    }
    const float asf = loadF(a_s, f, fas), adf = loadF(a_d, f, fad);
#pragma unroll
    for (int j = 0; j < 4; ++j) {
        const int row = row0 + w * 4 + j;
        h[(size_t)row * 64 + f] = __float2bfloat16(acc[j]);
        float ps = acc[j] * asf, pd = acc[j] * adf;
#pragma unroll
        for (int off = 32; off; off >>= 1) {
            ps += __shfl_xor(ps, off, 64);
            pd += __shfl_xor(pd, off, 64);
        }
        if (f == 0) { als[row] = ps; ald[row] = pd; }
    }
}

// ---------------- layer-2 GEMM: h2 = relu(agg+b1)@W2(64,64), in-place on agg ----------------
__global__ __launch_bounds__(256) void k_gemm2(
    __hip_bfloat16* __restrict__ agg, const void* __restrict__ b1,
    const void* __restrict__ W, const void* __restrict__ a_s,
    const void* __restrict__ a_d, const int* __restrict__ flags,
    float* __restrict__ als, float* __restrict__ ald)
{
    __shared__ float sW[64 * 64];
    __shared__ float sX[16 * 64];
    const int tid = threadIdx.x;
    const int fb = flags[4], fw = flags[5], fas = flags[6], fad = flags[7];
    for (int i = tid; i < 64 * 64; i += 256) sW[i] = loadF(W, i, fw);
    const int row0 = blockIdx.x * 16;
    for (int i = tid; i < 16 * 64; i += 256) {
        float v = b2f(agg[(size_t)row0 * 64 + i]) + loadF(b1, i & 63, fb);
        sX[i] = v > 0.f ? v : 0.f;
    }
    __syncthreads();

    const int w = tid >> 6, f = tid & 63;
    float acc[4] = {0.f, 0.f, 0.f, 0.f};
    const float* xb = &sX[(w * 4) * 64];
#pragma unroll 4
    for (int k = 0; k < 64; ++k) {
        float wv = sW[k * 64 + f];
        acc[0] = fmaf(xb[k],       wv, acc[0]);
        acc[1] = fmaf(xb[64 + k],  wv, acc[1]);
        acc[2] = fmaf(xb[128 + k], wv, acc[2]);
        acc[3] = fmaf(xb[192 + k], wv, acc[3]);
    }
    const float asf = loadF(a_s, f, fas), adf = loadF(a_d, f, fad);
#pragma unroll
    for (int j = 0; j < 4; ++j) {
        const int row = row0 + w * 4 + j;
        agg[(size_t)row * 64 + f] = __float2bfloat16(acc[j]);  // in-place: block owns these rows
        float ps = acc[j] * asf, pd = acc[j] * adf;
#pragma unroll
        for (int off = 32; off; off >>= 1) {
            ps += __shfl_xor(ps, off, 64);
            pd += __shfl_xor(pd, off, 64);
        }
        if (f == 0) { als[row] = ps; ald[row] = pd; }
    }
}

// ---------------- CSR gather: 1 node/wave, 8 edges/iter, 16B/lane loads ----------------
// lane = eg*8 + fg: edge-slot eg (0..7), feature-group fg (features fg*8..fg*8+7)
// softmax w/o max-subtraction: logits are O(10) (validated rounds 2-3)
__global__ __launch_bounds__(256) void k_gather(
    const int* __restrict__ row_ptr, const int* __restrict__ col,
    const float* __restrict__ als, const float* __restrict__ ald,
    const __hip_bfloat16* __restrict__ h,
    __hip_bfloat16* __restrict__ agg_out,   // layer-1 mode (final_out == null)
    void* __restrict__ final_out,           // layer-2 mode: write d_out with bias
    const void* __restrict__ bias, const int* __restrict__ flags, int N)
{
    const int tid = threadIdx.x;
    const int d = blockIdx.x * 4 + (tid >> 6);
    if (d >= N) return;
    const int lane = tid & 63;
    const int eg = lane >> 3, fg = lane & 7;
    const float aldd = ald[d];
    const int beg = row_ptr[d], end = row_ptr[d + 1];   // end > beg (self-loop)
    float acc[8] = {0.f,0.f,0.f,0.f,0.f,0.f,0.f,0.f};
    float den = 0.f;
    for (int j0 = beg; j0 < end; j0 += 8) {
        const int je = j0 + eg;
        const bool act = je < end;
        const int s = col[act ? je : end - 1];          // clamp: w=0 kills contribution
        const float w = act ? __expf(lrelu(als[s] + aldd)) : 0.f;
        den += w;
        const uint4 hv = *reinterpret_cast<const uint4*>(h + (size_t)s * 64 + fg * 8);
        acc[0] = fmaf(w, __uint_as_float(hv.x << 16),          acc[0]);
        acc[1] = fmaf(w, __uint_as_float(hv.x & 0xFFFF0000u),  acc[1]);
        acc[2] = fmaf(w, __uint_as_float(hv.y << 16),          acc[2]);
        acc[3] = fmaf(w, __uint_as_float(hv.y & 0xFFFF0000u),  acc[3]);
        acc[4] = fmaf(w, __uint_as_float(hv.z << 16),          acc[4]);
        acc[5] = fmaf(w, __uint_as_float(hv.z & 0xFFFF0000u),  acc[5]);
        acc[6] = fmaf(w, __uint_as_float(hv.w << 16),          acc[6]);
        acc[7] = fmaf(w, __uint_as_float(hv.w & 0xFFFF0000u),  acc[7]);
    }
#pragma unroll
    for (int off = 8; off <= 32; off <<= 1) {
        den += __shfl_xor(den, off, 64);
#pragma unroll
        for (int k = 0; k < 8; ++k) acc[k] += __shfl_xor(acc[k], off, 64);
    }
    if (eg != 0) return;
    const float inv = 1.f / den;
    if (final_out) {
        float vb[8];
#pragma unroll
        for (int k = 0; k < 8; ++k) vb[k] = acc[k] * inv + loadF(bias, fg * 8 + k, flags[8]);
        if (flags[0]) {
            float4* o = (float4*)((float*)final_out + (size_t)d * 64 + fg * 8);
            o[0] = make_float4(vb[0], vb[1], vb[2], vb[3]);
            o[1] = make_float4(vb[4], vb[5], vb[6], vb[7]);
        } else {
            uint4 o;
            o.x = (unsigned)f2bu(vb[0]) | ((unsigned)f2bu(vb[1]) << 16);
            o.y = (unsigned)f2bu(vb[2]) | ((unsigned)f2bu(vb[3]) << 16);
            o.z = (unsigned)f2bu(vb[4]) | ((unsigned)f2bu(vb[5]) << 16);
            o.w = (unsigned)f2bu(vb[6]) | ((unsigned)f2bu(vb[7]) << 16);
            *reinterpret_cast<uint4*>((__hip_bfloat16*)final_out + (size_t)d * 64 + fg * 8) = o;
        }
    } else {
        uint4 o;
        o.x = (unsigned)f2bu(acc[0] * inv) | ((unsigned)f2bu(acc[1] * inv) << 16);
        o.y = (unsigned)f2bu(acc[2] * inv) | ((unsigned)f2bu(acc[3] * inv) << 16);
        o.z = (unsigned)f2bu(acc[4] * inv) | ((unsigned)f2bu(acc[5] * inv) << 16);
        o.w = (unsigned)f2bu(acc[6] * inv) | ((unsigned)f2bu(acc[7] * inv) << 16);
        *reinterpret_cast<uint4*>(agg_out + (size_t)d * 64 + fg * 8) = o;
    }
}

extern "C" void kernel_launch(void* const* d_in, const int* in_sizes, int n_in,
                              void* d_out, int out_size, void* d_ws, size_t ws_size,
                              hipStream_t stream)
{
    const void* x   = d_in[0];
    const int*  ei  = (const int*)d_in[1];
    const void* W1  = d_in[2];
    const void* as1 = d_in[3];
    const void* ad1 = d_in[4];
    const void* b1  = d_in[5];
    const void* W2  = d_in[6];
    const void* as2 = d_in[7];
    const void* ad2 = d_in[8];
    const void* b2  = d_in[9];

    const int N  = in_sizes[0] / 128;   // 50000
    const int E  = in_sizes[1] / 2;     // 800000
    const int EA = E + N;
    const int* src = ei;
    const int* dst = ei + E;

    // workspace layout (64B-aligned blocks, ~17 MB total)
    uintptr_t base = (uintptr_t)d_ws;
    auto alloc = [&](size_t bytes) { uintptr_t p = base; base += (bytes + 63) & ~(size_t)63; return p; };
    int*   flags   = (int*)alloc(64 * 4);
    float* als     = (float*)alloc((size_t)N * 4);
    float* ald     = (float*)alloc((size_t)N * 4);
    int*   row_ptr = (int*)alloc((size_t)(N + 1) * 4);
    int*   deg_cur = (int*)alloc((size_t)N * 4);
    int*   bsum    = (int*)alloc(1024 * 4);
    int*   col     = (int*)alloc((size_t)EA * 4);
    __hip_bfloat16* hbuf   = (__hip_bfloat16*)alloc((size_t)N * 64 * 2);
    __hip_bfloat16* aggbuf = (__hip_bfloat16*)alloc((size_t)N * 64 * 2);

    const int eb = (EA + 255) / 256;
    const int nb = (N + 3) / 4;           // gather: 4 waves/block, 1 node/wave
    const int gb = (N + 15) / 16;         // gemm: 16 rows/block
    const int SB = (N + 256) / 256;       // scan blocks covering N+1 positions

    k_detect<<<1, 256, 0, stream>>>(
        x, in_sizes[0], W1, in_sizes[2], as1, in_sizes[3], ad1, in_sizes[4],
        b1, in_sizes[5], W2, in_sizes[6], as2, in_sizes[7], ad2, in_sizes[8],
        b2, in_sizes[9], flags);

    // ---- CSR build (once; shared by both layers) ----
    hipMemsetAsync(deg_cur, 0, (size_t)N * 4, stream);
    k_degree<<<eb, 256, 0, stream>>>(src, dst, deg_cur, E, EA);
    k_scan_blk<<<SB, 256, 0, stream>>>(deg_cur, row_ptr, bsum, N);
    k_scan_top<<<1, 256, 0, stream>>>(bsum, SB);
    k_scan_add<<<SB, 256, 0, stream>>>(row_ptr, bsum, N);
    hipMemsetAsync(deg_cur, 0, (size_t)N * 4, stream);
    k_fill<<<eb, 256, 0, stream>>>(src, dst, row_ptr, deg_cur, col, E, EA);

    // ---- layer 1 ----
    k_gemm1<<<gb, 256, 0, stream>>>(x, W1, as1, ad1, flags, hbuf, als, ald);
    k_gather<<<nb, 256, 0, stream>>>(row_ptr, col, als, ald, hbuf, aggbuf,
                                     nullptr, nullptr, flags, N);
    // ---- layer 2 ----
    k_gemm2<<<gb, 256, 0, stream>>>(aggbuf, b1, W2, as2, ad2, flags, als, ald);
    k_gather<<<nb, 256, 0, stream>>>(row_ptr, col, als, ald, aggbuf, nullptr,
                                     d_out, b2, flags, N);
    (void)out_size; (void)ws_size; (void)n_in;
}

// Round 5
// 276.113 us; speedup vs baseline: 2.6092x; 1.1959x over previous
//
#include <hip/hip_runtime.h>
#include <hip/hip_bf16.h>

#define DEV static __device__ __forceinline__

typedef short bf16x8 __attribute__((ext_vector_type(8)));
typedef float f32x4  __attribute__((ext_vector_type(4)));

union U4 { uint4 u; bf16x8 s; };

DEV float b2f(__hip_bfloat16 v) { return __bfloat162float(v); }
DEV float lrelu(float e) { return e > 0.f ? e : 0.2f * e; }

DEV unsigned short f2bu(float f) {
    __hip_bfloat16 b = __float2bfloat16(f);
    return *reinterpret_cast<unsigned short*>(&b);
}
DEV float bu2f(unsigned short u) { return __uint_as_float((unsigned)u << 16); }

// Flag-dispatched load (flag is wave-uniform).
DEV float loadF(const void* p, size_t i, int f32) {
    if (f32) return ((const float*)p)[i];
    return b2f(((const __hip_bfloat16*)p)[i]);
}

DEV uint4 pack8(const unsigned short* t) {
    uint4 v;
    v.x = (unsigned)t[0] | ((unsigned)t[1] << 16);
    v.y = (unsigned)t[2] | ((unsigned)t[3] << 16);
    v.z = (unsigned)t[4] | ((unsigned)t[5] << 16);
    v.w = (unsigned)t[6] | ((unsigned)t[7] << 16);
    return v;
}

// ---------------- dtype detection (validated rounds 2-4) ----------------
__global__ __launch_bounds__(256) void k_detect(
    const void* a0, int n0, const void* a1, int n1, const void* a2, int n2,
    const void* a3, int n3, const void* a4, int n4, const void* a5, int n5,
    const void* a6, int n6, const void* a7, int n7, const void* a8, int n8,
    int* __restrict__ flags)
{
    const void* ps[9] = {a0,a1,a2,a3,a4,a5,a6,a7,a8};
    const int   ns[9] = {n0,n1,n2,n3,n4,n5,n6,n7,n8};
    __shared__ int cnt;
    for (int k = 0; k < 9; ++k) {
        if (threadIdx.x == 0) cnt = 0;
        __syncthreads();
        int samples = ns[k] < 256 ? ns[k] : 256;
        if ((int)threadIdx.x < samples) {
            unsigned short u = ((const unsigned short*)ps[k])[threadIdx.x];
            unsigned e = (u >> 7) & 0xFFu;
            bool insane = (e >= 0xC8u) || (e == 0u && (u & 0x7Fu) != 0u);
            if (insane) atomicAdd(&cnt, 1);
        }
        __syncthreads();
        if (threadIdx.x == 0) flags[k] = (cnt >= 1) ? 1 : 0;
        __syncthreads();
    }
}

DEV void edge_sd(int i, int E, const int* __restrict__ src, const int* __restrict__ dst,
                 int& s, int& d) {
    if (i < E) { s = src[i]; d = dst[i]; }
    else       { s = d = i - E; }  // self-loops appended as arange(N)
}

// ---------------- CSR build ----------------
__global__ __launch_bounds__(256) void k_degree(
    const int* __restrict__ src, const int* __restrict__ dst,
    int* __restrict__ deg, int E, int EA)
{
    int i = blockIdx.x * 256 + threadIdx.x;
    if (i >= EA) return;
    int s, d; edge_sd(i, E, src, dst, s, d);
    atomicAdd(&deg[d], 1);
}

__global__ __launch_bounds__(256) void k_scan_blk(
    const int* __restrict__ deg, int* __restrict__ row_ptr,
    int* __restrict__ bsum, int N)
{
    __shared__ int sm[256];
    const int tid = threadIdx.x;
    const int gid = blockIdx.x * 256 + tid;
    int v = (gid < N) ? deg[gid] : 0;
    sm[tid] = v;
    __syncthreads();
#pragma unroll
    for (int off = 1; off < 256; off <<= 1) {
        int t = (tid >= off) ? sm[tid - off] : 0;
        __syncthreads();
        sm[tid] += t;
        __syncthreads();
    }
    if (gid <= N) row_ptr[gid] = sm[tid] - v;
    if (tid == 255) bsum[blockIdx.x] = sm[255];
}

__global__ __launch_bounds__(256) void k_scan_top(int* __restrict__ bsum, int SB)
{
    __shared__ int sm[256];
    const int tid = threadIdx.x;
    const int chunk = (SB + 255) / 256;
    const int lo = tid * chunk;
    const int hi = (lo + chunk < SB) ? lo + chunk : SB;
    int s = 0;
    for (int i = lo; i < hi; ++i) s += bsum[i];
    sm[tid] = s;
    __syncthreads();
#pragma unroll
    for (int off = 1; off < 256; off <<= 1) {
        int t = (tid >= off) ? sm[tid - off] : 0;
        __syncthreads();
        sm[tid] += t;
        __syncthreads();
    }
    int base = tid ? sm[tid - 1] : 0;
    for (int i = lo; i < hi; ++i) { int t = bsum[i]; bsum[i] = base; base += t; }
}

__global__ __launch_bounds__(256) void k_scan_add(
    int* __restrict__ row_ptr, const int* __restrict__ bsum, int N)
{
    int gid = blockIdx.x * 256 + threadIdx.x;
    if (gid <= N) row_ptr[gid] += bsum[blockIdx.x];
}

__global__ __launch_bounds__(256) void k_fill(
    const int* __restrict__ src, const int* __restrict__ dst,
    const int* __restrict__ row_ptr, int* __restrict__ cursor,
    int* __restrict__ col, int E, int EA)
{
    int i = blockIdx.x * 256 + threadIdx.x;
    if (i >= EA) return;
    int s, d; edge_sd(i, E, src, dst, s, d);
    int pos = atomicAdd(&cursor[d], 1);
    col[row_ptr[d] + pos] = s;
}

// ---------------- MFMA layer-1 GEMM: h = x(N,128)@W1(128,64) + fused logits ----------------
// 64 rows/block. sA[r][k] stride 136 (2-way-free banks, 16B aligned rows).
// sB = W^T: sB[n][k] stride 136. Frags via ds_read_b128.
__global__ __launch_bounds__(256) void k_gemm1(
    const void* __restrict__ x, const void* __restrict__ W,
    const void* __restrict__ a_s, const void* __restrict__ a_d,
    const int* __restrict__ flags,
    __hip_bfloat16* __restrict__ h, float* __restrict__ als, float* __restrict__ ald,
    int N)
{
    __shared__ __align__(16) unsigned short sMem[2 * 64 * 136];
    __shared__ float sAs[64], sAd[64];
    unsigned short* sA = sMem;
    unsigned short* sB = sMem + 64 * 136;
    float* sOut = (float*)sMem;              // overlay (64*68 f32 = 17408 B)

    const int tid = threadIdx.x;
    const int row0 = blockIdx.x * 64;
    const int fx = flags[0], fw = flags[1];

    if (tid < 64) sAs[tid] = loadF(a_s, tid, flags[2]);
    else if (tid < 128) sAd[tid - 64] = loadF(a_d, tid - 64, flags[3]);

    // ---- stage x rows -> sA ----
    if (!fx) {
        const uint4* xg = (const uint4*)x;   // 16 uint4 per row
#pragma unroll
        for (int it = 0; it < 2; ++it) {
            int g = tid + it * 256;          // 0..511
            int r = g >> 4, c16 = g & 15;
            uint4 v = (row0 + r < N) ? xg[(size_t)(row0 + r) * 16 + c16]
                                     : make_uint4(0, 0, 0, 0);
            *(uint4*)(sA + r * 136 + c16 * 8) = v;
        }
    } else {
        for (int i = tid; i < 64 * 128; i += 256) {
            int r = i >> 7, k = i & 127;
            float v = (row0 + r < N) ? ((const float*)x)[(size_t)(row0 + r) * 128 + k] : 0.f;
            sA[r * 136 + k] = f2bu(v);
        }
    }
    // ---- stage W^T -> sB ----
    if (!fw) {
        const unsigned short* Wg = (const unsigned short*)W;
        const int n = tid & 63;
        int k0 = (tid >> 6) * 8;
#pragma unroll
        for (int rep = 0; rep < 4; ++rep, k0 += 32) {
            unsigned short t[8];
#pragma unroll
            for (int j = 0; j < 8; ++j) t[j] = Wg[(size_t)(k0 + j) * 64 + n];
            *(uint4*)(sB + n * 136 + k0) = pack8(t);
        }
    } else {
        const float* Wg = (const float*)W;
        for (int i = tid; i < 128 * 64; i += 256) {
            int k = i >> 6, n = i & 63;
            sB[n * 136 + k] = f2bu(Wg[i]);
        }
    }
    __syncthreads();

    // ---- MFMA compute: wave w owns rows m0..m0+15, all 4 col tiles ----
    const int w = tid >> 6, lane = tid & 63;
    const int m0 = w * 16;
    const int qr = lane >> 4;                // quad
    const int lc = lane & 15;

    bf16x8 afrag[4];
#pragma unroll
    for (int c = 0; c < 4; ++c) {
        U4 u; u.u = *(const uint4*)(sA + (m0 + lc) * 136 + c * 32 + qr * 8);
        afrag[c] = u.s;
    }
    f32x4 accs[4];
#pragma unroll
    for (int nt = 0; nt < 4; ++nt) {
        f32x4 acc = {0.f, 0.f, 0.f, 0.f};
#pragma unroll
        for (int c = 0; c < 4; ++c) {
            U4 u; u.u = *(const uint4*)(sB + (nt * 16 + lc) * 136 + c * 32 + qr * 8);
            acc = __builtin_amdgcn_mfma_f32_16x16x32_bf16(afrag[c], u.s, acc, 0, 0, 0);
        }
        accs[nt] = acc;
    }
    __syncthreads();                          // done with sA/sB; overlay sOut

    // D layout: col = lane&15, row = quad*4 + reg (HW-verified)
#pragma unroll
    for (int nt = 0; nt < 4; ++nt)
#pragma unroll
        for (int reg = 0; reg < 4; ++reg)
            sOut[(m0 + qr * 4 + reg) * 68 + nt * 16 + lc] = accs[nt][reg];
    __syncthreads();

    // ---- epilogue: coalesced h store + fused logits ----
    {
        const int r = tid >> 2, seg = tid & 3;
        const int row = row0 + r;
        const float* po = sOut + r * 68 + seg * 16;
        float ps = 0.f, pd = 0.f;
        unsigned short ob[16];
#pragma unroll
        for (int i = 0; i < 16; ++i) {
            float v = po[i];
            ps = fmaf(v, sAs[seg * 16 + i], ps);
            pd = fmaf(v, sAd[seg * 16 + i], pd);
            ob[i] = f2bu(v);
        }
        if (row < N) {
            uint4* hp = (uint4*)((unsigned short*)h + (size_t)row * 64 + seg * 16);
            hp[0] = pack8(ob);
            hp[1] = pack8(ob + 8);
        }
        ps += __shfl_xor(ps, 1, 64); ps += __shfl_xor(ps, 2, 64);
        pd += __shfl_xor(pd, 1, 64); pd += __shfl_xor(pd, 2, 64);
        if (seg == 0 && row < N) { als[row] = ps; ald[row] = pd; }
    }
}

// ---------------- MFMA layer-2 GEMM: h2 = relu(agg+b1)@W2(64,64), in-place ----------------
__global__ __launch_bounds__(256) void k_gemm2(
    __hip_bfloat16* __restrict__ agg, const void* __restrict__ b1,
    const void* __restrict__ W, const void* __restrict__ a_s,
    const void* __restrict__ a_d, const int* __restrict__ flags,
    float* __restrict__ als, float* __restrict__ ald, int N)
{
    __shared__ __align__(16) unsigned short sMem[2 * 64 * 72];
    __shared__ float sAs[64], sAd[64], sBias[64];
    unsigned short* sA = sMem;
    unsigned short* sB = sMem + 64 * 72;
    float* sOut = (float*)sMem;              // 17408 B <= 18432 B

    const int tid = threadIdx.x;
    const int row0 = blockIdx.x * 64;
    const int fw = flags[5];

    if (tid < 64) sAs[tid] = loadF(a_s, tid, flags[6]);
    else if (tid < 128) sAd[tid - 64] = loadF(a_d, tid - 64, flags[7]);
    else if (tid < 192) sBias[tid - 128] = loadF(b1, tid - 128, flags[4]);
    __syncthreads();                          // sBias needed for A staging

    // ---- stage relu(agg + b1) -> sA (agg is our bf16 buffer) ----
    {
        const uint4* ag = (const uint4*)agg;  // 8 uint4 per row
#pragma unroll
        for (int it = 0; it < 2; ++it) {
            int g = tid + it * 256;           // 0..511
            int r = g >> 3, c8 = g & 7;
            uint4 v = (row0 + r < N) ? ag[(size_t)(row0 + r) * 8 + c8]
                                     : make_uint4(0, 0, 0, 0);
            unsigned short in[8] = {
                (unsigned short)(v.x & 0xFFFF), (unsigned short)(v.x >> 16),
                (unsigned short)(v.y & 0xFFFF), (unsigned short)(v.y >> 16),
                (unsigned short)(v.z & 0xFFFF), (unsigned short)(v.z >> 16),
                (unsigned short)(v.w & 0xFFFF), (unsigned short)(v.w >> 16)};
            unsigned short ob[8];
#pragma unroll
            for (int j = 0; j < 8; ++j) {
                float t = bu2f(in[j]) + sBias[c8 * 8 + j];
                ob[j] = f2bu(t > 0.f ? t : 0.f);
            }
            *(uint4*)(sA + r * 72 + c8 * 8) = pack8(ob);
        }
    }
    // ---- stage W2^T -> sB ----
    if (!fw) {
        const unsigned short* Wg = (const unsigned short*)W;
        const int n = tid & 63;
        int k0 = (tid >> 6) * 8;
#pragma unroll
        for (int rep = 0; rep < 2; ++rep, k0 += 32) {
            unsigned short t[8];
#pragma unroll
            for (int j = 0; j < 8; ++j) t[j] = Wg[(size_t)(k0 + j) * 64 + n];
            *(uint4*)(sB + n * 72 + k0) = pack8(t);
        }
    } else {
        const float* Wg = (const float*)W;
        for (int i = tid; i < 64 * 64; i += 256) {
            int k = i >> 6, n = i & 63;
            sB[n * 72 + k] = f2bu(Wg[i]);
        }
    }
    __syncthreads();

    const int w = tid >> 6, lane = tid & 63;
    const int m0 = w * 16;
    const int qr = lane >> 4, lc = lane & 15;

    bf16x8 afrag[2];
#pragma unroll
    for (int c = 0; c < 2; ++c) {
        U4 u; u.u = *(const uint4*)(sA + (m0 + lc) * 72 + c * 32 + qr * 8);
        afrag[c] = u.s;
    }
    f32x4 accs[4];
#pragma unroll
    for (int nt = 0; nt < 4; ++nt) {
        f32x4 acc = {0.f, 0.f, 0.f, 0.f};
#pragma unroll
        for (int c = 0; c < 2; ++c) {
            U4 u; u.u = *(const uint4*)(sB + (nt * 16 + lc) * 72 + c * 32 + qr * 8);
            acc = __builtin_amdgcn_mfma_f32_16x16x32_bf16(afrag[c], u.s, acc, 0, 0, 0);
        }
        accs[nt] = acc;
    }
    __syncthreads();
#pragma unroll
    for (int nt = 0; nt < 4; ++nt)
#pragma unroll
        for (int reg = 0; reg < 4; ++reg)
            sOut[(m0 + qr * 4 + reg) * 68 + nt * 16 + lc] = accs[nt][reg];
    __syncthreads();

    {
        const int r = tid >> 2, seg = tid & 3;
        const int row = row0 + r;
        const float* po = sOut + r * 68 + seg * 16;
        float ps = 0.f, pd = 0.f;
        unsigned short ob[16];
#pragma unroll
        for (int i = 0; i < 16; ++i) {
            float v = po[i];
            ps = fmaf(v, sAs[seg * 16 + i], ps);
            pd = fmaf(v, sAd[seg * 16 + i], pd);
            ob[i] = f2bu(v);
        }
        if (row < N) {
            uint4* hp = (uint4*)((unsigned short*)agg + (size_t)row * 64 + seg * 16);
            hp[0] = pack8(ob);
            hp[1] = pack8(ob + 8);
        }
        ps += __shfl_xor(ps, 1, 64); ps += __shfl_xor(ps, 2, 64);
        pd += __shfl_xor(pd, 1, 64); pd += __shfl_xor(pd, 2, 64);
        if (seg == 0 && row < N) { als[row] = ps; ald[row] = pd; }
    }
}

// ---------------- CSR gather: 1 node/wave, 8 edges/iter, 16B/lane (round-4, kept) ----------------
__global__ __launch_bounds__(256) void k_gather(
    const int* __restrict__ row_ptr, const int* __restrict__ col,
    const float* __restrict__ als, const float* __restrict__ ald,
    const __hip_bfloat16* __restrict__ h,
    __hip_bfloat16* __restrict__ agg_out,
    void* __restrict__ final_out,
    const void* __restrict__ bias, const int* __restrict__ flags, int N)
{
    const int tid = threadIdx.x;
    const int d = blockIdx.x * 4 + (tid >> 6);
    if (d >= N) return;
    const int lane = tid & 63;
    const int eg = lane >> 3, fg = lane & 7;
    const float aldd = ald[d];
    const int beg = row_ptr[d], end = row_ptr[d + 1];
    float acc[8] = {0.f,0.f,0.f,0.f,0.f,0.f,0.f,0.f};
    float den = 0.f;
    for (int j0 = beg; j0 < end; j0 += 8) {
        const int je = j0 + eg;
        const bool act = je < end;
        const int s = col[act ? je : end - 1];
        const float w = act ? __expf(lrelu(als[s] + aldd)) : 0.f;
        den += w;
        const uint4 hv = *reinterpret_cast<const uint4*>(h + (size_t)s * 64 + fg * 8);
        acc[0] = fmaf(w, __uint_as_float(hv.x << 16),          acc[0]);
        acc[1] = fmaf(w, __uint_as_float(hv.x & 0xFFFF0000u),  acc[1]);
        acc[2] = fmaf(w, __uint_as_float(hv.y << 16),          acc[2]);
        acc[3] = fmaf(w, __uint_as_float(hv.y & 0xFFFF0000u),  acc[3]);
        acc[4] = fmaf(w, __uint_as_float(hv.z << 16),          acc[4]);
        acc[5] = fmaf(w, __uint_as_float(hv.z & 0xFFFF0000u),  acc[5]);
        acc[6] = fmaf(w, __uint_as_float(hv.w << 16),          acc[6]);
        acc[7] = fmaf(w, __uint_as_float(hv.w & 0xFFFF0000u),  acc[7]);
    }
#pragma unroll
    for (int off = 8; off <= 32; off <<= 1) {
        den += __shfl_xor(den, off, 64);
#pragma unroll
        for (int k = 0; k < 8; ++k) acc[k] += __shfl_xor(acc[k], off, 64);
    }
    if (eg != 0) return;
    const float inv = 1.f / den;
    if (final_out) {
        float vb[8];
#pragma unroll
        for (int k = 0; k < 8; ++k) vb[k] = acc[k] * inv + loadF(bias, fg * 8 + k, flags[8]);
        if (flags[0]) {
            float4* o = (float4*)((float*)final_out + (size_t)d * 64 + fg * 8);
            o[0] = make_float4(vb[0], vb[1], vb[2], vb[3]);
            o[1] = make_float4(vb[4], vb[5], vb[6], vb[7]);
        } else {
            unsigned short ob[8];
#pragma unroll
            for (int k = 0; k < 8; ++k) ob[k] = f2bu(vb[k]);
            *reinterpret_cast<uint4*>((__hip_bfloat16*)final_out + (size_t)d * 64 + fg * 8) = pack8(ob);
        }
    } else {
        unsigned short ob[8];
#pragma unroll
        for (int k = 0; k < 8; ++k) ob[k] = f2bu(acc[k] * inv);
        *reinterpret_cast<uint4*>(agg_out + (size_t)d * 64 + fg * 8) = pack8(ob);
    }
}

extern "C" void kernel_launch(void* const* d_in, const int* in_sizes, int n_in,
                              void* d_out, int out_size, void* d_ws, size_t ws_size,
                              hipStream_t stream)
{
    const void* x   = d_in[0];
    const int*  ei  = (const int*)d_in[1];
    const void* W1  = d_in[2];
    const void* as1 = d_in[3];
    const void* ad1 = d_in[4];
    const void* b1  = d_in[5];
    const void* W2  = d_in[6];
    const void* as2 = d_in[7];
    const void* ad2 = d_in[8];
    const void* b2  = d_in[9];

    const int N  = in_sizes[0] / 128;   // 50000
    const int E  = in_sizes[1] / 2;     // 800000
    const int EA = E + N;
    const int* src = ei;
    const int* dst = ei + E;

    uintptr_t base = (uintptr_t)d_ws;
    auto alloc = [&](size_t bytes) { uintptr_t p = base; base += (bytes + 63) & ~(size_t)63; return p; };
    int*   flags   = (int*)alloc(64 * 4);
    float* als     = (float*)alloc((size_t)N * 4);
    float* ald     = (float*)alloc((size_t)N * 4);
    int*   row_ptr = (int*)alloc((size_t)(N + 1) * 4);
    int*   deg_cur = (int*)alloc((size_t)N * 4);
    int*   bsum    = (int*)alloc(1024 * 4);
    int*   col     = (int*)alloc((size_t)EA * 4);
    __hip_bfloat16* hbuf   = (__hip_bfloat16*)alloc((size_t)N * 64 * 2);
    __hip_bfloat16* aggbuf = (__hip_bfloat16*)alloc((size_t)N * 64 * 2);

    const int eb = (EA + 255) / 256;
    const int nb = (N + 3) / 4;           // gather: 4 waves/block
    const int gb = (N + 63) / 64;         // mfma gemm: 64 rows/block
    const int SB = (N + 256) / 256;

    k_detect<<<1, 256, 0, stream>>>(
        x, in_sizes[0], W1, in_sizes[2], as1, in_sizes[3], ad1, in_sizes[4],
        b1, in_sizes[5], W2, in_sizes[6], as2, in_sizes[7], ad2, in_sizes[8],
        b2, in_sizes[9], flags);

    // ---- CSR build (once; shared by both layers) ----
    hipMemsetAsync(deg_cur, 0, (size_t)N * 4, stream);
    k_degree<<<eb, 256, 0, stream>>>(src, dst, deg_cur, E, EA);
    k_scan_blk<<<SB, 256, 0, stream>>>(deg_cur, row_ptr, bsum, N);
    k_scan_top<<<1, 256, 0, stream>>>(bsum, SB);
    k_scan_add<<<SB, 256, 0, stream>>>(row_ptr, bsum, N);
    hipMemsetAsync(deg_cur, 0, (size_t)N * 4, stream);
    k_fill<<<eb, 256, 0, stream>>>(src, dst, row_ptr, deg_cur, col, E, EA);

    // ---- layer 1 ----
    k_gemm1<<<gb, 256, 0, stream>>>(x, W1, as1, ad1, flags, hbuf, als, ald, N);
    k_gather<<<nb, 256, 0, stream>>>(row_ptr, col, als, ald, hbuf, aggbuf,
                                     nullptr, nullptr, flags, N);
    // ---- layer 2 ----
    k_gemm2<<<gb, 256, 0, stream>>>(aggbuf, b1, W2, as2, ad2, flags, als, ald, N);
    k_gather<<<nb, 256, 0, stream>>>(row_ptr, col, als, ald, aggbuf, nullptr,
                                     d_out, b2, flags, N);
    (void)out_size; (void)ws_size; (void)n_in;
}

// Round 6
// 230.553 us; speedup vs baseline: 3.1248x; 1.1976x over previous
//
#include <hip/hip_runtime.h>
#include <hip/hip_bf16.h>

#define DEV static __device__ __forceinline__

typedef short bf16x8 __attribute__((ext_vector_type(8)));
typedef float f32x4  __attribute__((ext_vector_type(4)));

union U4 { uint4 u; bf16x8 s; };

DEV float b2f(__hip_bfloat16 v) { return __bfloat162float(v); }
DEV float lrelu(float e) { return e > 0.f ? e : 0.2f * e; }

DEV unsigned short f2bu(float f) {
    __hip_bfloat16 b = __float2bfloat16(f);
    return *reinterpret_cast<unsigned short*>(&b);
}
DEV float bu2f(unsigned short u) { return __uint_as_float((unsigned)u << 16); }

DEV float loadF(const void* p, size_t i, int f32) {
    if (f32) return ((const float*)p)[i];
    return b2f(((const __hip_bfloat16*)p)[i]);
}

DEV uint4 pack8(const unsigned short* t) {
    uint4 v;
    v.x = (unsigned)t[0] | ((unsigned)t[1] << 16);
    v.y = (unsigned)t[2] | ((unsigned)t[3] << 16);
    v.z = (unsigned)t[4] | ((unsigned)t[5] << 16);
    v.w = (unsigned)t[6] | ((unsigned)t[7] << 16);
    return v;
}

// ---------------- dtype detection (validated rounds 2-5) ----------------
__global__ __launch_bounds__(256) void k_detect(
    const void* a0, int n0, const void* a1, int n1, const void* a2, int n2,
    const void* a3, int n3, const void* a4, int n4, const void* a5, int n5,
    const void* a6, int n6, const void* a7, int n7, const void* a8, int n8,
    int* __restrict__ flags)
{
    const void* ps[9] = {a0,a1,a2,a3,a4,a5,a6,a7,a8};
    const int   ns[9] = {n0,n1,n2,n3,n4,n5,n6,n7,n8};
    __shared__ int cnt;
    for (int k = 0; k < 9; ++k) {
        if (threadIdx.x == 0) cnt = 0;
        __syncthreads();
        int samples = ns[k] < 256 ? ns[k] : 256;
        if ((int)threadIdx.x < samples) {
            unsigned short u = ((const unsigned short*)ps[k])[threadIdx.x];
            unsigned e = (u >> 7) & 0xFFu;
            bool insane = (e >= 0xC8u) || (e == 0u && (u & 0x7Fu) != 0u);
            if (insane) atomicAdd(&cnt, 1);
        }
        __syncthreads();
        if (threadIdx.x == 0) flags[k] = (cnt >= 1) ? 1 : 0;
        __syncthreads();
    }
}

DEV void edge_sd(int i, int E, const int* __restrict__ src, const int* __restrict__ dst,
                 int& s, int& d) {
    if (i < E) { s = src[i]; d = dst[i]; }
    else       { s = d = i - E; }  // self-loops appended as arange(N)
}

// ---------------- binned CSR build: 256-node buckets, coalesced writes ----------------
// Requires N <= 2^17 (s packed in 17 bits) and N <= 65536? no: NBK=(N+255)/256 <= 256
// -> N <= 65536. Holds for N=50000.
#define G_BIN 128

__global__ __launch_bounds__(256) void k_binA(
    const int* __restrict__ src, const int* __restrict__ dst,
    int* __restrict__ hist, int E, int EA, int chunk)
{
    __shared__ int cnt[256];
    const int tid = threadIdx.x;
    cnt[tid] = 0;
    __syncthreads();
    const int lo = blockIdx.x * chunk;
    const int hi = min(lo + chunk, EA);
    for (int i = lo + tid; i < hi; i += 256) {
        int s, d; edge_sd(i, E, src, dst, s, d);
        atomicAdd(&cnt[d >> 8], 1);
    }
    __syncthreads();
    hist[blockIdx.x * 256 + tid] = cnt[tid];
}

__global__ __launch_bounds__(256) void k_binB(
    const int* __restrict__ hist, int* __restrict__ offs,
    int* __restrict__ bstart)
{
    __shared__ int sm[256];
    const int tid = threadIdx.x;
    int total = 0;
    for (int blk = 0; blk < G_BIN; ++blk) total += hist[blk * 256 + tid];
    sm[tid] = total;
    __syncthreads();
#pragma unroll
    for (int off = 1; off < 256; off <<= 1) {
        int t = (tid >= off) ? sm[tid - off] : 0;
        __syncthreads();
        sm[tid] += t;
        __syncthreads();
    }
    int b0 = sm[tid] - total;          // exclusive bucket start
    bstart[tid] = b0;
    if (tid == 255) bstart[256] = sm[255];
    int run = b0;
    for (int blk = 0; blk < G_BIN; ++blk) {
        offs[blk * 256 + tid] = run;
        run += hist[blk * 256 + tid];
    }
}

__global__ __launch_bounds__(256) void k_binC(
    const int* __restrict__ src, const int* __restrict__ dst,
    const int* __restrict__ offs, unsigned* __restrict__ ebuf,
    int E, int EA, int chunk)
{
    __shared__ int cur[256];
    const int tid = threadIdx.x;
    cur[tid] = offs[blockIdx.x * 256 + tid];
    __syncthreads();
    const int lo = blockIdx.x * chunk;
    const int hi = min(lo + chunk, EA);
    for (int i = lo + tid; i < hi; i += 256) {
        int s, d; edge_sd(i, E, src, dst, s, d);
        int pos = atomicAdd(&cur[d >> 8], 1);
        ebuf[pos] = ((unsigned)(d & 255) << 17) | (unsigned)s;
    }
}

__global__ __launch_bounds__(256) void k_binD(
    const unsigned* __restrict__ ebuf, const int* __restrict__ bstart,
    int* __restrict__ row_ptr, int* __restrict__ col, int N)
{
    __shared__ int cnt[256];
    __shared__ int pfx[256];
    const int tid = threadIdx.x;
    const int b = blockIdx.x;
    const int lo = bstart[b], hi = bstart[b + 1];
    cnt[tid] = 0;
    __syncthreads();
    for (int i = lo + tid; i < hi; i += 256)
        atomicAdd(&cnt[ebuf[i] >> 17], 1);
    __syncthreads();
    const int c = cnt[tid];
    pfx[tid] = c;
    __syncthreads();
#pragma unroll
    for (int off = 1; off < 256; off <<= 1) {
        int t = (tid >= off) ? pfx[tid - off] : 0;
        __syncthreads();
        pfx[tid] += t;
        __syncthreads();
    }
    const int excl = pfx[tid] - c;
    const int d = b * 256 + tid;
    if (d <= N) row_ptr[d] = lo + excl;
    __syncthreads();
    cnt[tid] = lo + excl;              // reuse as absolute cursor
    __syncthreads();
    for (int i = lo + tid; i < hi; i += 256) {
        unsigned v = ebuf[i];
        int pos = atomicAdd(&cnt[v >> 17], 1);
        col[pos] = (int)(v & 0x1FFFFu);
    }
}

// ---------------- MFMA layer-1 GEMM: h = x(N,128)@W1(128,64) + fused logits ----------------
__global__ __launch_bounds__(256) void k_gemm1(
    const void* __restrict__ x, const void* __restrict__ W,
    const void* __restrict__ a_s, const void* __restrict__ a_d,
    const int* __restrict__ flags,
    __hip_bfloat16* __restrict__ h, float* __restrict__ als, float* __restrict__ ald,
    int N)
{
    __shared__ __align__(16) unsigned short sMem[2 * 64 * 136];
    __shared__ float sAs[64], sAd[64];
    unsigned short* sA = sMem;
    unsigned short* sB = sMem + 64 * 136;
    float* sOut = (float*)sMem;

    const int tid = threadIdx.x;
    const int row0 = blockIdx.x * 64;
    const int fx = flags[0], fw = flags[1];

    if (tid < 64) sAs[tid] = loadF(a_s, tid, flags[2]);
    else if (tid < 128) sAd[tid - 64] = loadF(a_d, tid - 64, flags[3]);

    if (!fx) {
        const uint4* xg = (const uint4*)x;
#pragma unroll
        for (int it = 0; it < 2; ++it) {
            int g = tid + it * 256;
            int r = g >> 4, c16 = g & 15;
            uint4 v = (row0 + r < N) ? xg[(size_t)(row0 + r) * 16 + c16]
                                     : make_uint4(0, 0, 0, 0);
            *(uint4*)(sA + r * 136 + c16 * 8) = v;
        }
    } else {
        for (int i = tid; i < 64 * 128; i += 256) {
            int r = i >> 7, k = i & 127;
            float v = (row0 + r < N) ? ((const float*)x)[(size_t)(row0 + r) * 128 + k] : 0.f;
            sA[r * 136 + k] = f2bu(v);
        }
    }
    if (!fw) {
        const unsigned short* Wg = (const unsigned short*)W;
        const int n = tid & 63;
        int k0 = (tid >> 6) * 8;
#pragma unroll
        for (int rep = 0; rep < 4; ++rep, k0 += 32) {
            unsigned short t[8];
#pragma unroll
            for (int j = 0; j < 8; ++j) t[j] = Wg[(size_t)(k0 + j) * 64 + n];
            *(uint4*)(sB + n * 136 + k0) = pack8(t);
        }
    } else {
        const float* Wg = (const float*)W;
        for (int i = tid; i < 128 * 64; i += 256) {
            int k = i >> 6, n = i & 63;
            sB[n * 136 + k] = f2bu(Wg[i]);
        }
    }
    __syncthreads();

    const int w = tid >> 6, lane = tid & 63;
    const int m0 = w * 16;
    const int qr = lane >> 4;
    const int lc = lane & 15;

    bf16x8 afrag[4];
#pragma unroll
    for (int c = 0; c < 4; ++c) {
        U4 u; u.u = *(const uint4*)(sA + (m0 + lc) * 136 + c * 32 + qr * 8);
        afrag[c] = u.s;
    }
    f32x4 accs[4];
#pragma unroll
    for (int nt = 0; nt < 4; ++nt) {
        f32x4 acc = {0.f, 0.f, 0.f, 0.f};
#pragma unroll
        for (int c = 0; c < 4; ++c) {
            U4 u; u.u = *(const uint4*)(sB + (nt * 16 + lc) * 136 + c * 32 + qr * 8);
            acc = __builtin_amdgcn_mfma_f32_16x16x32_bf16(afrag[c], u.s, acc, 0, 0, 0);
        }
        accs[nt] = acc;
    }
    __syncthreads();

#pragma unroll
    for (int nt = 0; nt < 4; ++nt)
#pragma unroll
        for (int reg = 0; reg < 4; ++reg)
            sOut[(m0 + qr * 4 + reg) * 68 + nt * 16 + lc] = accs[nt][reg];
    __syncthreads();

    {
        const int r = tid >> 2, seg = tid & 3;
        const int row = row0 + r;
        const float* po = sOut + r * 68 + seg * 16;
        float ps = 0.f, pd = 0.f;
        unsigned short ob[16];
#pragma unroll
        for (int i = 0; i < 16; ++i) {
            float v = po[i];
            ps = fmaf(v, sAs[seg * 16 + i], ps);
            pd = fmaf(v, sAd[seg * 16 + i], pd);
            ob[i] = f2bu(v);
        }
        if (row < N) {
            uint4* hp = (uint4*)((unsigned short*)h + (size_t)row * 64 + seg * 16);
            hp[0] = pack8(ob);
            hp[1] = pack8(ob + 8);
        }
        ps += __shfl_xor(ps, 1, 64); ps += __shfl_xor(ps, 2, 64);
        pd += __shfl_xor(pd, 1, 64); pd += __shfl_xor(pd, 2, 64);
        if (seg == 0 && row < N) { als[row] = ps; ald[row] = pd; }
    }
}

// ---------------- MFMA layer-2 GEMM: h2 = relu(agg+b1)@W2(64,64), in-place ----------------
__global__ __launch_bounds__(256) void k_gemm2(
    __hip_bfloat16* __restrict__ agg, const void* __restrict__ b1,
    const void* __restrict__ W, const void* __restrict__ a_s,
    const void* __restrict__ a_d, const int* __restrict__ flags,
    float* __restrict__ als, float* __restrict__ ald, int N)
{
    __shared__ __align__(16) unsigned short sMem[2 * 64 * 72];
    __shared__ float sAs[64], sAd[64], sBias[64];
    unsigned short* sA = sMem;
    unsigned short* sB = sMem + 64 * 72;
    float* sOut = (float*)sMem;

    const int tid = threadIdx.x;
    const int row0 = blockIdx.x * 64;
    const int fw = flags[5];

    if (tid < 64) sAs[tid] = loadF(a_s, tid, flags[6]);
    else if (tid < 128) sAd[tid - 64] = loadF(a_d, tid - 64, flags[7]);
    else if (tid < 192) sBias[tid - 128] = loadF(b1, tid - 128, flags[4]);
    __syncthreads();

    {
        const uint4* ag = (const uint4*)agg;
#pragma unroll
        for (int it = 0; it < 2; ++it) {
            int g = tid + it * 256;
            int r = g >> 3, c8 = g & 7;
            uint4 v = (row0 + r < N) ? ag[(size_t)(row0 + r) * 8 + c8]
                                     : make_uint4(0, 0, 0, 0);
            unsigned short in[8] = {
                (unsigned short)(v.x & 0xFFFF), (unsigned short)(v.x >> 16),
                (unsigned short)(v.y & 0xFFFF), (unsigned short)(v.y >> 16),
                (unsigned short)(v.z & 0xFFFF), (unsigned short)(v.z >> 16),
                (unsigned short)(v.w & 0xFFFF), (unsigned short)(v.w >> 16)};
            unsigned short ob[8];
#pragma unroll
            for (int j = 0; j < 8; ++j) {
                float t = bu2f(in[j]) + sBias[c8 * 8 + j];
                ob[j] = f2bu(t > 0.f ? t : 0.f);
            }
            *(uint4*)(sA + r * 72 + c8 * 8) = pack8(ob);
        }
    }
    if (!fw) {
        const unsigned short* Wg = (const unsigned short*)W;
        const int n = tid & 63;
        int k0 = (tid >> 6) * 8;
#pragma unroll
        for (int rep = 0; rep < 2; ++rep, k0 += 32) {
            unsigned short t[8];
#pragma unroll
            for (int j = 0; j < 8; ++j) t[j] = Wg[(size_t)(k0 + j) * 64 + n];
            *(uint4*)(sB + n * 72 + k0) = pack8(t);
        }
    } else {
        const float* Wg = (const float*)W;
        for (int i = tid; i < 64 * 64; i += 256) {
            int k = i >> 6, n = i & 63;
            sB[n * 72 + k] = f2bu(Wg[i]);
        }
    }
    __syncthreads();

    const int w = tid >> 6, lane = tid & 63;
    const int m0 = w * 16;
    const int qr = lane >> 4, lc = lane & 15;

    bf16x8 afrag[2];
#pragma unroll
    for (int c = 0; c < 2; ++c) {
        U4 u; u.u = *(const uint4*)(sA + (m0 + lc) * 72 + c * 32 + qr * 8);
        afrag[c] = u.s;
    }
    f32x4 accs[4];
#pragma unroll
    for (int nt = 0; nt < 4; ++nt) {
        f32x4 acc = {0.f, 0.f, 0.f, 0.f};
#pragma unroll
        for (int c = 0; c < 2; ++c) {
            U4 u; u.u = *(const uint4*)(sB + (nt * 16 + lc) * 72 + c * 32 + qr * 8);
            acc = __builtin_amdgcn_mfma_f32_16x16x32_bf16(afrag[c], u.s, acc, 0, 0, 0);
        }
        accs[nt] = acc;
    }
    __syncthreads();
#pragma unroll
    for (int nt = 0; nt < 4; ++nt)
#pragma unroll
        for (int reg = 0; reg < 4; ++reg)
            sOut[(m0 + qr * 4 + reg) * 68 + nt * 16 + lc] = accs[nt][reg];
    __syncthreads();

    {
        const int r = tid >> 2, seg = tid & 3;
        const int row = row0 + r;
        const float* po = sOut + r * 68 + seg * 16;
        float ps = 0.f, pd = 0.f;
        unsigned short ob[16];
#pragma unroll
        for (int i = 0; i < 16; ++i) {
            float v = po[i];
            ps = fmaf(v, sAs[seg * 16 + i], ps);
            pd = fmaf(v, sAd[seg * 16 + i], pd);
            ob[i] = f2bu(v);
        }
        if (row < N) {
            uint4* hp = (uint4*)((unsigned short*)agg + (size_t)row * 64 + seg * 16);
            hp[0] = pack8(ob);
            hp[1] = pack8(ob + 8);
        }
        ps += __shfl_xor(ps, 1, 64); ps += __shfl_xor(ps, 2, 64);
        pd += __shfl_xor(pd, 1, 64); pd += __shfl_xor(pd, 2, 64);
        if (seg == 0 && row < N) { als[row] = ps; ald[row] = pd; }
    }
}

// ---------------- CSR gather: 1 node/wave, 8 edges/iter, 16B/lane (rounds 4-5) ----------------
__global__ __launch_bounds__(256) void k_gather(
    const int* __restrict__ row_ptr, const int* __restrict__ col,
    const float* __restrict__ als, const float* __restrict__ ald,
    const __hip_bfloat16* __restrict__ h,
    __hip_bfloat16* __restrict__ agg_out,
    void* __restrict__ final_out,
    const void* __restrict__ bias, const int* __restrict__ flags, int N)
{
    const int tid = threadIdx.x;
    const int d = blockIdx.x * 4 + (tid >> 6);
    if (d >= N) return;
    const int lane = tid & 63;
    const int eg = lane >> 3, fg = lane & 7;
    const float aldd = ald[d];
    const int beg = row_ptr[d], end = row_ptr[d + 1];
    float acc[8] = {0.f,0.f,0.f,0.f,0.f,0.f,0.f,0.f};
    float den = 0.f;
    for (int j0 = beg; j0 < end; j0 += 8) {
        const int je = j0 + eg;
        const bool act = je < end;
        const int s = col[act ? je : end - 1];
        const float w = act ? __expf(lrelu(als[s] + aldd)) : 0.f;
        den += w;
        const uint4 hv = *reinterpret_cast<const uint4*>(h + (size_t)s * 64 + fg * 8);
        acc[0] = fmaf(w, __uint_as_float(hv.x << 16),          acc[0]);
        acc[1] = fmaf(w, __uint_as_float(hv.x & 0xFFFF0000u),  acc[1]);
        acc[2] = fmaf(w, __uint_as_float(hv.y << 16),          acc[2]);
        acc[3] = fmaf(w, __uint_as_float(hv.y & 0xFFFF0000u),  acc[3]);
        acc[4] = fmaf(w, __uint_as_float(hv.z << 16),          acc[4]);
        acc[5] = fmaf(w, __uint_as_float(hv.z & 0xFFFF0000u),  acc[5]);
        acc[6] = fmaf(w, __uint_as_float(hv.w << 16),          acc[6]);
        acc[7] = fmaf(w, __uint_as_float(hv.w & 0xFFFF0000u),  acc[7]);
    }
#pragma unroll
    for (int off = 8; off <= 32; off <<= 1) {
        den += __shfl_xor(den, off, 64);
#pragma unroll
        for (int k = 0; k < 8; ++k) acc[k] += __shfl_xor(acc[k], off, 64);
    }
    if (eg != 0) return;
    const float inv = 1.f / den;
    if (final_out) {
        float vb[8];
#pragma unroll
        for (int k = 0; k < 8; ++k) vb[k] = acc[k] * inv + loadF(bias, fg * 8 + k, flags[8]);
        if (flags[0]) {
            float4* o = (float4*)((float*)final_out + (size_t)d * 64 + fg * 8);
            o[0] = make_float4(vb[0], vb[1], vb[2], vb[3]);
            o[1] = make_float4(vb[4], vb[5], vb[6], vb[7]);
        } else {
            unsigned short ob[8];
#pragma unroll
            for (int k = 0; k < 8; ++k) ob[k] = f2bu(vb[k]);
            *reinterpret_cast<uint4*>((__hip_bfloat16*)final_out + (size_t)d * 64 + fg * 8) = pack8(ob);
        }
    } else {
        unsigned short ob[8];
#pragma unroll
        for (int k = 0; k < 8; ++k) ob[k] = f2bu(acc[k] * inv);
        *reinterpret_cast<uint4*>(agg_out + (size_t)d * 64 + fg * 8) = pack8(ob);
    }
}

extern "C" void kernel_launch(void* const* d_in, const int* in_sizes, int n_in,
                              void* d_out, int out_size, void* d_ws, size_t ws_size,
                              hipStream_t stream)
{
    const void* x   = d_in[0];
    const int*  ei  = (const int*)d_in[1];
    const void* W1  = d_in[2];
    const void* as1 = d_in[3];
    const void* ad1 = d_in[4];
    const void* b1  = d_in[5];
    const void* W2  = d_in[6];
    const void* as2 = d_in[7];
    const void* ad2 = d_in[8];
    const void* b2  = d_in[9];

    const int N  = in_sizes[0] / 128;   // 50000
    const int E  = in_sizes[1] / 2;     // 800000
    const int EA = E + N;
    const int* src = ei;
    const int* dst = ei + E;

    uintptr_t base = (uintptr_t)d_ws;
    auto alloc = [&](size_t bytes) { uintptr_t p = base; base += (bytes + 63) & ~(size_t)63; return p; };
    int*      flags   = (int*)alloc(64 * 4);
    float*    als     = (float*)alloc((size_t)N * 4);
    float*    ald     = (float*)alloc((size_t)N * 4);
    int*      row_ptr = (int*)alloc((size_t)(N + 1) * 4);
    int*      hist    = (int*)alloc((size_t)G_BIN * 256 * 4);
    int*      offs    = (int*)alloc((size_t)G_BIN * 256 * 4);
    int*      bstart  = (int*)alloc(257 * 4);
    unsigned* ebuf    = (unsigned*)alloc((size_t)EA * 4);
    int*      col     = (int*)alloc((size_t)EA * 4);
    __hip_bfloat16* hbuf   = (__hip_bfloat16*)alloc((size_t)N * 64 * 2);
    __hip_bfloat16* aggbuf = (__hip_bfloat16*)alloc((size_t)N * 64 * 2);

    const int nb  = (N + 3) / 4;          // gather: 4 waves/block
    const int gb  = (N + 63) / 64;        // mfma gemm: 64 rows/block
    const int NBK = (N + 255) / 256;      // dst buckets (<= 256)
    const int chunk = (EA + G_BIN - 1) / G_BIN;

    k_detect<<<1, 256, 0, stream>>>(
        x, in_sizes[0], W1, in_sizes[2], as1, in_sizes[3], ad1, in_sizes[4],
        b1, in_sizes[5], W2, in_sizes[6], as2, in_sizes[7], ad2, in_sizes[8],
        b2, in_sizes[9], flags);

    // ---- binned CSR build (once; shared by both layers) ----
    k_binA<<<G_BIN, 256, 0, stream>>>(src, dst, hist, E, EA, chunk);
    k_binB<<<1, 256, 0, stream>>>(hist, offs, bstart);
    k_binC<<<G_BIN, 256, 0, stream>>>(src, dst, offs, ebuf, E, EA, chunk);
    k_binD<<<NBK, 256, 0, stream>>>(ebuf, bstart, row_ptr, col, N);

    // ---- layer 1 ----
    k_gemm1<<<gb, 256, 0, stream>>>(x, W1, as1, ad1, flags, hbuf, als, ald, N);
    k_gather<<<nb, 256, 0, stream>>>(row_ptr, col, als, ald, hbuf, aggbuf,
                                     nullptr, nullptr, flags, N);
    // ---- layer 2 ----
    k_gemm2<<<gb, 256, 0, stream>>>(aggbuf, b1, W2, as2, ad2, flags, als, ald, N);
    k_gather<<<nb, 256, 0, stream>>>(row_ptr, col, als, ald, aggbuf, nullptr,
                                     d_out, b2, flags, N);
    (void)out_size; (void)ws_size; (void)n_in;
}

// Round 7
// 227.180 us; speedup vs baseline: 3.1712x; 1.0148x over previous
//
#include <hip/hip_runtime.h>
#include <hip/hip_bf16.h>

#define DEV static __device__ __forceinline__

typedef short bf16x8 __attribute__((ext_vector_type(8)));
typedef float f32x4  __attribute__((ext_vector_type(4)));

union U4 { uint4 u; bf16x8 s; };

DEV float b2f(__hip_bfloat16 v) { return __bfloat162float(v); }
DEV float lrelu(float e) { return e > 0.f ? e : 0.2f * e; }

DEV unsigned short f2bu(float f) {
    __hip_bfloat16 b = __float2bfloat16(f);
    return *reinterpret_cast<unsigned short*>(&b);
}
DEV float bu2f(unsigned short u) { return __uint_as_float((unsigned)u << 16); }

DEV float loadF(const void* p, size_t i, int f32) {
    if (f32) return ((const float*)p)[i];
    return b2f(((const __hip_bfloat16*)p)[i]);
}

DEV uint4 pack8(const unsigned short* t) {
    uint4 v;
    v.x = (unsigned)t[0] | ((unsigned)t[1] << 16);
    v.y = (unsigned)t[2] | ((unsigned)t[3] << 16);
    v.z = (unsigned)t[4] | ((unsigned)t[5] << 16);
    v.w = (unsigned)t[6] | ((unsigned)t[7] << 16);
    return v;
}

// ---------------- dtype detection (validated rounds 2-6) ----------------
__global__ __launch_bounds__(256) void k_detect(
    const void* a0, int n0, const void* a1, int n1, const void* a2, int n2,
    const void* a3, int n3, const void* a4, int n4, const void* a5, int n5,
    const void* a6, int n6, const void* a7, int n7, const void* a8, int n8,
    int* __restrict__ flags)
{
    const void* ps[9] = {a0,a1,a2,a3,a4,a5,a6,a7,a8};
    const int   ns[9] = {n0,n1,n2,n3,n4,n5,n6,n7,n8};
    __shared__ int cnt;
    for (int k = 0; k < 9; ++k) {
        if (threadIdx.x == 0) cnt = 0;
        __syncthreads();
        int samples = ns[k] < 256 ? ns[k] : 256;
        if ((int)threadIdx.x < samples) {
            unsigned short u = ((const unsigned short*)ps[k])[threadIdx.x];
            unsigned e = (u >> 7) & 0xFFu;
            bool insane = (e >= 0xC8u) || (e == 0u && (u & 0x7Fu) != 0u);
            if (insane) atomicAdd(&cnt, 1);
        }
        __syncthreads();
        if (threadIdx.x == 0) flags[k] = (cnt >= 1) ? 1 : 0;
        __syncthreads();
    }
}

DEV void edge_sd(int i, int E, const int* __restrict__ src, const int* __restrict__ dst,
                 int& s, int& d) {
    if (i < E) { s = src[i]; d = dst[i]; }
    else       { s = d = i - E; }  // self-loops appended as arange(N)
}

// ---------------- binned CSR build: 256-node buckets, coalesced writes ----------------
#define G_BIN 128

__global__ __launch_bounds__(256) void k_binA(
    const int* __restrict__ src, const int* __restrict__ dst,
    int* __restrict__ hist, int E, int EA, int chunk)
{
    __shared__ int cnt[256];
    const int tid = threadIdx.x;
    cnt[tid] = 0;
    __syncthreads();
    const int lo = blockIdx.x * chunk;
    const int hi = min(lo + chunk, EA);
    for (int i = lo + tid; i < hi; i += 256) {
        int s, d; edge_sd(i, E, src, dst, s, d);
        atomicAdd(&cnt[d >> 8], 1);
    }
    __syncthreads();
    hist[blockIdx.x * 256 + tid] = cnt[tid];
}

__global__ __launch_bounds__(256) void k_binB(
    const int* __restrict__ hist, int* __restrict__ offs,
    int* __restrict__ bstart)
{
    __shared__ int sm[256];
    const int tid = threadIdx.x;
    int total = 0;
    for (int blk = 0; blk < G_BIN; ++blk) total += hist[blk * 256 + tid];
    sm[tid] = total;
    __syncthreads();
#pragma unroll
    for (int off = 1; off < 256; off <<= 1) {
        int t = (tid >= off) ? sm[tid - off] : 0;
        __syncthreads();
        sm[tid] += t;
        __syncthreads();
    }
    int b0 = sm[tid] - total;          // exclusive bucket start
    bstart[tid] = b0;
    if (tid == 255) bstart[256] = sm[255];
    int run = b0;
    for (int blk = 0; blk < G_BIN; ++blk) {
        offs[blk * 256 + tid] = run;
        run += hist[blk * 256 + tid];
    }
}

__global__ __launch_bounds__(256) void k_binC(
    const int* __restrict__ src, const int* __restrict__ dst,
    const int* __restrict__ offs, unsigned* __restrict__ ebuf,
    int E, int EA, int chunk)
{
    __shared__ int cur[256];
    const int tid = threadIdx.x;
    cur[tid] = offs[blockIdx.x * 256 + tid];
    __syncthreads();
    const int lo = blockIdx.x * chunk;
    const int hi = min(lo + chunk, EA);
    for (int i = lo + tid; i < hi; i += 256) {
        int s, d; edge_sd(i, E, src, dst, s, d);
        int pos = atomicAdd(&cur[d >> 8], 1);
        ebuf[pos] = ((unsigned)(d & 255) << 17) | (unsigned)s;
    }
}

__global__ __launch_bounds__(256) void k_binD(
    const unsigned* __restrict__ ebuf, const int* __restrict__ bstart,
    int* __restrict__ row_ptr, int* __restrict__ col, int N)
{
    __shared__ int cnt[256];
    __shared__ int pfx[256];
    const int tid = threadIdx.x;
    const int b = blockIdx.x;
    const int lo = bstart[b], hi = bstart[b + 1];
    cnt[tid] = 0;
    __syncthreads();
    for (int i = lo + tid; i < hi; i += 256)
        atomicAdd(&cnt[ebuf[i] >> 17], 1);
    __syncthreads();
    const int c = cnt[tid];
    pfx[tid] = c;
    __syncthreads();
#pragma unroll
    for (int off = 1; off < 256; off <<= 1) {
        int t = (tid >= off) ? pfx[tid - off] : 0;
        __syncthreads();
        pfx[tid] += t;
        __syncthreads();
    }
    const int excl = pfx[tid] - c;
    const int d = b * 256 + tid;
    if (d <= N) row_ptr[d] = lo + excl;
    __syncthreads();
    cnt[tid] = lo + excl;              // reuse as absolute cursor
    __syncthreads();
    for (int i = lo + tid; i < hi; i += 256) {
        unsigned v = ebuf[i];
        int pos = atomicAdd(&cnt[v >> 17], 1);
        col[pos] = (int)(v & 0x1FFFFu);
    }
}

// ---------------- MFMA layer-1 GEMM: h = x(N,128)@W1(128,64) + fused logits ----------------
__global__ __launch_bounds__(256) void k_gemm1(
    const void* __restrict__ x, const void* __restrict__ W,
    const void* __restrict__ a_s, const void* __restrict__ a_d,
    const int* __restrict__ flags,
    __hip_bfloat16* __restrict__ h, float* __restrict__ als, float* __restrict__ ald,
    int N)
{
    __shared__ __align__(16) unsigned short sMem[2 * 64 * 136];
    __shared__ float sAs[64], sAd[64];
    unsigned short* sA = sMem;
    unsigned short* sB = sMem + 64 * 136;
    float* sOut = (float*)sMem;

    const int tid = threadIdx.x;
    const int row0 = blockIdx.x * 64;
    const int fx = flags[0], fw = flags[1];

    if (tid < 64) sAs[tid] = loadF(a_s, tid, flags[2]);
    else if (tid < 128) sAd[tid - 64] = loadF(a_d, tid - 64, flags[3]);

    if (!fx) {
        const uint4* xg = (const uint4*)x;
#pragma unroll
        for (int it = 0; it < 2; ++it) {
            int g = tid + it * 256;
            int r = g >> 4, c16 = g & 15;
            uint4 v = (row0 + r < N) ? xg[(size_t)(row0 + r) * 16 + c16]
                                     : make_uint4(0, 0, 0, 0);
            *(uint4*)(sA + r * 136 + c16 * 8) = v;
        }
    } else {
        for (int i = tid; i < 64 * 128; i += 256) {
            int r = i >> 7, k = i & 127;
            float v = (row0 + r < N) ? ((const float*)x)[(size_t)(row0 + r) * 128 + k] : 0.f;
            sA[r * 136 + k] = f2bu(v);
        }
    }
    if (!fw) {
        const unsigned short* Wg = (const unsigned short*)W;
        const int n = tid & 63;
        int k0 = (tid >> 6) * 8;
#pragma unroll
        for (int rep = 0; rep < 4; ++rep, k0 += 32) {
            unsigned short t[8];
#pragma unroll
            for (int j = 0; j < 8; ++j) t[j] = Wg[(size_t)(k0 + j) * 64 + n];
            *(uint4*)(sB + n * 136 + k0) = pack8(t);
        }
    } else {
        const float* Wg = (const float*)W;
        for (int i = tid; i < 128 * 64; i += 256) {
            int k = i >> 6, n = i & 63;
            sB[n * 136 + k] = f2bu(Wg[i]);
        }
    }
    __syncthreads();

    const int w = tid >> 6, lane = tid & 63;
    const int m0 = w * 16;
    const int qr = lane >> 4;
    const int lc = lane & 15;

    bf16x8 afrag[4];
#pragma unroll
    for (int c = 0; c < 4; ++c) {
        U4 u; u.u = *(const uint4*)(sA + (m0 + lc) * 136 + c * 32 + qr * 8);
        afrag[c] = u.s;
    }
    f32x4 accs[4];
#pragma unroll
    for (int nt = 0; nt < 4; ++nt) {
        f32x4 acc = {0.f, 0.f, 0.f, 0.f};
#pragma unroll
        for (int c = 0; c < 4; ++c) {
            U4 u; u.u = *(const uint4*)(sB + (nt * 16 + lc) * 136 + c * 32 + qr * 8);
            acc = __builtin_amdgcn_mfma_f32_16x16x32_bf16(afrag[c], u.s, acc, 0, 0, 0);
        }
        accs[nt] = acc;
    }
    __syncthreads();

#pragma unroll
    for (int nt = 0; nt < 4; ++nt)
#pragma unroll
        for (int reg = 0; reg < 4; ++reg)
            sOut[(m0 + qr * 4 + reg) * 68 + nt * 16 + lc] = accs[nt][reg];
    __syncthreads();

    {
        const int r = tid >> 2, seg = tid & 3;
        const int row = row0 + r;
        const float* po = sOut + r * 68 + seg * 16;
        float ps = 0.f, pd = 0.f;
        unsigned short ob[16];
#pragma unroll
        for (int i = 0; i < 16; ++i) {
            float v = po[i];
            ps = fmaf(v, sAs[seg * 16 + i], ps);
            pd = fmaf(v, sAd[seg * 16 + i], pd);
            ob[i] = f2bu(v);
        }
        if (row < N) {
            uint4* hp = (uint4*)((unsigned short*)h + (size_t)row * 64 + seg * 16);
            hp[0] = pack8(ob);
            hp[1] = pack8(ob + 8);
        }
        ps += __shfl_xor(ps, 1, 64); ps += __shfl_xor(ps, 2, 64);
        pd += __shfl_xor(pd, 1, 64); pd += __shfl_xor(pd, 2, 64);
        if (seg == 0 && row < N) { als[row] = ps; ald[row] = pd; }
    }
}

// ---------------- MFMA layer-2 GEMM: h2 = relu(agg+b1)@W2(64,64), in-place ----------------
__global__ __launch_bounds__(256) void k_gemm2(
    __hip_bfloat16* __restrict__ agg, const void* __restrict__ b1,
    const void* __restrict__ W, const void* __restrict__ a_s,
    const void* __restrict__ a_d, const int* __restrict__ flags,
    float* __restrict__ als, float* __restrict__ ald, int N)
{
    __shared__ __align__(16) unsigned short sMem[2 * 64 * 72];
    __shared__ float sAs[64], sAd[64], sBias[64];
    unsigned short* sA = sMem;
    unsigned short* sB = sMem + 64 * 72;
    float* sOut = (float*)sMem;

    const int tid = threadIdx.x;
    const int row0 = blockIdx.x * 64;
    const int fw = flags[5];

    if (tid < 64) sAs[tid] = loadF(a_s, tid, flags[6]);
    else if (tid < 128) sAd[tid - 64] = loadF(a_d, tid - 64, flags[7]);
    else if (tid < 192) sBias[tid - 128] = loadF(b1, tid - 128, flags[4]);
    __syncthreads();

    {
        const uint4* ag = (const uint4*)agg;
#pragma unroll
        for (int it = 0; it < 2; ++it) {
            int g = tid + it * 256;
            int r = g >> 3, c8 = g & 7;
            uint4 v = (row0 + r < N) ? ag[(size_t)(row0 + r) * 8 + c8]
                                     : make_uint4(0, 0, 0, 0);
            unsigned short in[8] = {
                (unsigned short)(v.x & 0xFFFF), (unsigned short)(v.x >> 16),
                (unsigned short)(v.y & 0xFFFF), (unsigned short)(v.y >> 16),
                (unsigned short)(v.z & 0xFFFF), (unsigned short)(v.z >> 16),
                (unsigned short)(v.w & 0xFFFF), (unsigned short)(v.w >> 16)};
            unsigned short ob[8];
#pragma unroll
            for (int j = 0; j < 8; ++j) {
                float t = bu2f(in[j]) + sBias[c8 * 8 + j];
                ob[j] = f2bu(t > 0.f ? t : 0.f);
            }
            *(uint4*)(sA + r * 72 + c8 * 8) = pack8(ob);
        }
    }
    if (!fw) {
        const unsigned short* Wg = (const unsigned short*)W;
        const int n = tid & 63;
        int k0 = (tid >> 6) * 8;
#pragma unroll
        for (int rep = 0; rep < 2; ++rep, k0 += 32) {
            unsigned short t[8];
#pragma unroll
            for (int j = 0; j < 8; ++j) t[j] = Wg[(size_t)(k0 + j) * 64 + n];
            *(uint4*)(sB + n * 72 + k0) = pack8(t);
        }
    } else {
        const float* Wg = (const float*)W;
        for (int i = tid; i < 64 * 64; i += 256) {
            int k = i >> 6, n = i & 63;
            sB[n * 72 + k] = f2bu(Wg[i]);
        }
    }
    __syncthreads();

    const int w = tid >> 6, lane = tid & 63;
    const int m0 = w * 16;
    const int qr = lane >> 4, lc = lane & 15;

    bf16x8 afrag[2];
#pragma unroll
    for (int c = 0; c < 2; ++c) {
        U4 u; u.u = *(const uint4*)(sA + (m0 + lc) * 72 + c * 32 + qr * 8);
        afrag[c] = u.s;
    }
    f32x4 accs[4];
#pragma unroll
    for (int nt = 0; nt < 4; ++nt) {
        f32x4 acc = {0.f, 0.f, 0.f, 0.f};
#pragma unroll
        for (int c = 0; c < 2; ++c) {
            U4 u; u.u = *(const uint4*)(sB + (nt * 16 + lc) * 72 + c * 32 + qr * 8);
            acc = __builtin_amdgcn_mfma_f32_16x16x32_bf16(afrag[c], u.s, acc, 0, 0, 0);
        }
        accs[nt] = acc;
    }
    __syncthreads();
#pragma unroll
    for (int nt = 0; nt < 4; ++nt)
#pragma unroll
        for (int reg = 0; reg < 4; ++reg)
            sOut[(m0 + qr * 4 + reg) * 68 + nt * 16 + lc] = accs[nt][reg];
    __syncthreads();

    {
        const int r = tid >> 2, seg = tid & 3;
        const int row = row0 + r;
        const float* po = sOut + r * 68 + seg * 16;
        float ps = 0.f, pd = 0.f;
        unsigned short ob[16];
#pragma unroll
        for (int i = 0; i < 16; ++i) {
            float v = po[i];
            ps = fmaf(v, sAs[seg * 16 + i], ps);
            pd = fmaf(v, sAd[seg * 16 + i], pd);
            ob[i] = f2bu(v);
        }
        if (row < N) {
            uint4* hp = (uint4*)((unsigned short*)agg + (size_t)row * 64 + seg * 16);
            hp[0] = pack8(ob);
            hp[1] = pack8(ob + 8);
        }
        ps += __shfl_xor(ps, 1, 64); ps += __shfl_xor(ps, 2, 64);
        pd += __shfl_xor(pd, 1, 64); pd += __shfl_xor(pd, 2, 64);
        if (seg == 0 && row < N) { als[row] = ps; ald[row] = pd; }
    }
}

// ---------------- CSR gather: PERSISTENT waves, 1 node/wave-iter, 8 edges/step ----------------
// Grid sized so blocks stay resident (8 blocks/CU); each wave grid-strides over
// nodes. Fixes round-6's 8% occupancy (12500 short-lived blocks starved the CUs).
__global__ __launch_bounds__(256) void k_gather(
    const int* __restrict__ row_ptr, const int* __restrict__ col,
    const float* __restrict__ als, const float* __restrict__ ald,
    const __hip_bfloat16* __restrict__ h,
    __hip_bfloat16* __restrict__ agg_out,
    void* __restrict__ final_out,
    const void* __restrict__ bias, const int* __restrict__ flags, int N)
{
    const int tid = threadIdx.x;
    const int lane = tid & 63;
    const int eg = lane >> 3, fg = lane & 7;
    const int wid = blockIdx.x * 4 + (tid >> 6);
    const int nw  = gridDim.x * 4;

    for (int d = wid; d < N; d += nw) {
        const float aldd = ald[d];
        const int beg = row_ptr[d], end = row_ptr[d + 1];
        float acc[8] = {0.f,0.f,0.f,0.f,0.f,0.f,0.f,0.f};
        float den = 0.f;
        for (int j0 = beg; j0 < end; j0 += 8) {
            const int je = j0 + eg;
            const bool act = je < end;
            const int s = col[act ? je : end - 1];
            const float w = act ? __expf(lrelu(als[s] + aldd)) : 0.f;
            den += w;
            const uint4 hv = *reinterpret_cast<const uint4*>(h + (size_t)s * 64 + fg * 8);
            acc[0] = fmaf(w, __uint_as_float(hv.x << 16),          acc[0]);
            acc[1] = fmaf(w, __uint_as_float(hv.x & 0xFFFF0000u),  acc[1]);
            acc[2] = fmaf(w, __uint_as_float(hv.y << 16),          acc[2]);
            acc[3] = fmaf(w, __uint_as_float(hv.y & 0xFFFF0000u),  acc[3]);
            acc[4] = fmaf(w, __uint_as_float(hv.z << 16),          acc[4]);
            acc[5] = fmaf(w, __uint_as_float(hv.z & 0xFFFF0000u),  acc[5]);
            acc[6] = fmaf(w, __uint_as_float(hv.w << 16),          acc[6]);
            acc[7] = fmaf(w, __uint_as_float(hv.w & 0xFFFF0000u),  acc[7]);
        }
#pragma unroll
        for (int off = 8; off <= 32; off <<= 1) {
            den += __shfl_xor(den, off, 64);
#pragma unroll
            for (int k = 0; k < 8; ++k) acc[k] += __shfl_xor(acc[k], off, 64);
        }
        if (eg == 0) {
            const float inv = 1.f / den;
            if (final_out) {
                float vb[8];
#pragma unroll
                for (int k = 0; k < 8; ++k) vb[k] = acc[k] * inv + loadF(bias, fg * 8 + k, flags[8]);
                if (flags[0]) {
                    float4* o = (float4*)((float*)final_out + (size_t)d * 64 + fg * 8);
                    o[0] = make_float4(vb[0], vb[1], vb[2], vb[3]);
                    o[1] = make_float4(vb[4], vb[5], vb[6], vb[7]);
                } else {
                    unsigned short ob[8];
#pragma unroll
                    for (int k = 0; k < 8; ++k) ob[k] = f2bu(vb[k]);
                    *reinterpret_cast<uint4*>((__hip_bfloat16*)final_out + (size_t)d * 64 + fg * 8) = pack8(ob);
                }
            } else {
                unsigned short ob[8];
#pragma unroll
                for (int k = 0; k < 8; ++k) ob[k] = f2bu(acc[k] * inv);
                *reinterpret_cast<uint4*>(agg_out + (size_t)d * 64 + fg * 8) = pack8(ob);
            }
        }
    }
}

extern "C" void kernel_launch(void* const* d_in, const int* in_sizes, int n_in,
                              void* d_out, int out_size, void* d_ws, size_t ws_size,
                              hipStream_t stream)
{
    const void* x   = d_in[0];
    const int*  ei  = (const int*)d_in[1];
    const void* W1  = d_in[2];
    const void* as1 = d_in[3];
    const void* ad1 = d_in[4];
    const void* b1  = d_in[5];
    const void* W2  = d_in[6];
    const void* as2 = d_in[7];
    const void* ad2 = d_in[8];
    const void* b2  = d_in[9];

    const int N  = in_sizes[0] / 128;   // 50000
    const int E  = in_sizes[1] / 2;     // 800000
    const int EA = E + N;
    const int* src = ei;
    const int* dst = ei + E;

    uintptr_t base = (uintptr_t)d_ws;
    auto alloc = [&](size_t bytes) { uintptr_t p = base; base += (bytes + 63) & ~(size_t)63; return p; };
    int*      flags   = (int*)alloc(64 * 4);
    float*    als     = (float*)alloc((size_t)N * 4);
    float*    ald     = (float*)alloc((size_t)N * 4);
    int*      row_ptr = (int*)alloc((size_t)(N + 1) * 4);
    int*      hist    = (int*)alloc((size_t)G_BIN * 256 * 4);
    int*      offs    = (int*)alloc((size_t)G_BIN * 256 * 4);
    int*      bstart  = (int*)alloc(257 * 4);
    unsigned* ebuf    = (unsigned*)alloc((size_t)EA * 4);
    int*      col     = (int*)alloc((size_t)EA * 4);
    __hip_bfloat16* hbuf   = (__hip_bfloat16*)alloc((size_t)N * 64 * 2);
    __hip_bfloat16* aggbuf = (__hip_bfloat16*)alloc((size_t)N * 64 * 2);

    const int gatherb = 2048;             // persistent: 8 blocks/CU resident
    const int gb  = (N + 63) / 64;        // mfma gemm: 64 rows/block
    const int NBK = (N + 255) / 256;      // dst buckets (<= 256)
    const int chunk = (EA + G_BIN - 1) / G_BIN;

    k_detect<<<1, 256, 0, stream>>>(
        x, in_sizes[0], W1, in_sizes[2], as1, in_sizes[3], ad1, in_sizes[4],
        b1, in_sizes[5], W2, in_sizes[6], as2, in_sizes[7], ad2, in_sizes[8],
        b2, in_sizes[9], flags);

    // ---- binned CSR build (once; shared by both layers) ----
    k_binA<<<G_BIN, 256, 0, stream>>>(src, dst, hist, E, EA, chunk);
    k_binB<<<1, 256, 0, stream>>>(hist, offs, bstart);
    k_binC<<<G_BIN, 256, 0, stream>>>(src, dst, offs, ebuf, E, EA, chunk);
    k_binD<<<NBK, 256, 0, stream>>>(ebuf, bstart, row_ptr, col, N);

    // ---- layer 1 ----
    k_gemm1<<<gb, 256, 0, stream>>>(x, W1, as1, ad1, flags, hbuf, als, ald, N);
    k_gather<<<gatherb, 256, 0, stream>>>(row_ptr, col, als, ald, hbuf, aggbuf,
                                          nullptr, nullptr, flags, N);
    // ---- layer 2 ----
    k_gemm2<<<gb, 256, 0, stream>>>(aggbuf, b1, W2, as2, ad2, flags, als, ald, N);
    k_gather<<<gatherb, 256, 0, stream>>>(row_ptr, col, als, ald, aggbuf, nullptr,
                                          d_out, b2, flags, N);
    (void)out_size; (void)ws_size; (void)n_in;
}